// Round 23
// baseline (285.275 us; speedup 1.0000x reference)
//
#include <hip/hip_runtime.h>
#include <hip/hip_bf16.h>

#define B_ 4
#define S_ 2048
#define DM_ 512
#define H_ 4
#define DK_ 128
#define DI_ 1024
#define NV_ 5000

typedef __attribute__((ext_vector_type(8))) short bf16x8;
typedef __attribute__((ext_vector_type(8))) unsigned short u16x8;
typedef __attribute__((ext_vector_type(4))) unsigned short u16x4;
typedef __attribute__((ext_vector_type(4))) float f32x4;

__device__ inline unsigned short f2bf(float x) {
  unsigned int u = __float_as_uint(x);
  unsigned int r = (u + 0x7fffu + ((u >> 16) & 1u)) >> 16;
  return (unsigned short)r;
}
__device__ inline float bf2f(unsigned short u) {
  return __uint_as_float(((unsigned int)u) << 16);
}
__device__ inline void gload16(const void* g, void* l) {
  __builtin_amdgcn_global_load_lds(
      (const __attribute__((address_space(1))) void*)g,
      (__attribute__((address_space(3))) void*)l, 16, 0, 0);
}

// ---- kernel A: embed (0-8191) | wt (8192-10239) | AW=bf16(A*W*10) (10240-22447) ----
__global__ __launch_bounds__(256) void ew_kernel(
    const int* __restrict__ et, const int* __restrict__ vx,
    const float* __restrict__ tmv, const float* __restrict__ npm,
    const float* __restrict__ eemb, const float* __restrict__ vemb,
    const float* __restrict__ Wq, const float* __restrict__ Wk,
    const float* __restrict__ Wv, const float* __restrict__ Wo,
    const float* __restrict__ w1, const float* __restrict__ w2,
    const float* __restrict__ A, const float* __restrict__ W,
    float* __restrict__ enc0, unsigned short* __restrict__ enc0b,
    unsigned short* __restrict__ WqT, unsigned short* __restrict__ WkT,
    unsigned short* __restrict__ WvT, unsigned short* __restrict__ WoT,
    unsigned short* __restrict__ w1T, unsigned short* __restrict__ w2T,
    unsigned short* __restrict__ AWb, int useAW) {
  __shared__ unsigned short T[32][40];
  int bid = blockIdx.x;
  int tid = threadIdx.x;
  if (bid < 8192) {
    int row = bid;
    int t = et[row], v = vx[row];
    float time = tmv[row], mask = npm[row];
    #pragma unroll
    for (int k = 0; k < 2; ++k) {
      int dd = tid + k * 256;
      float pvinv = __expf((float)(dd & ~1) * -0.017988946039015984f);
      float r = time * pvinv;
      float tem = (((dd & 1) == 0) ? sinf(r) : cosf(r)) * mask;
      float val = eemb[(size_t)t * DM_ + dd] + vemb[(size_t)v * DM_ + dd] + tem;
      enc0[(size_t)row * DM_ + dd] = val;
      enc0b[(size_t)row * DM_ + dd] = f2bf(val);
    }
  } else if (bid < 10240) {
    int wb = bid - 8192;
    const float* src; unsigned short* dst; int K, N, lid;
    if (wb < 256)       { src = Wq; dst = WqT; K = 512;  N = 512;  lid = wb; }
    else if (wb < 512)  { src = Wk; dst = WkT; K = 512;  N = 512;  lid = wb - 256; }
    else if (wb < 768)  { src = Wv; dst = WvT; K = 512;  N = 512;  lid = wb - 512; }
    else if (wb < 1024) { src = Wo; dst = WoT; K = 512;  N = 512;  lid = wb - 768; }
    else if (wb < 1536) { src = w1; dst = w1T; K = 512;  N = 1024; lid = wb - 1024; }
    else                { src = w2; dst = w2T; K = 1024; N = 512;  lid = wb - 1536; }
    int nt = N / 32;
    int n0 = (lid % nt) * 32, k0 = (lid / nt) * 32;
    int r = tid >> 3, c0 = (tid & 7) * 4;
    float4 v = *(const float4*)&src[(size_t)(k0 + r) * N + n0 + c0];
    T[r][c0 + 0] = f2bf(v.x);
    T[r][c0 + 1] = f2bf(v.y);
    T[r][c0 + 2] = f2bf(v.z);
    T[r][c0 + 3] = f2bf(v.w);
    __syncthreads();
    u16x4 o;
    o[0] = T[c0 + 0][r]; o[1] = T[c0 + 1][r];
    o[2] = T[c0 + 2][r]; o[3] = T[c0 + 3][r];
    *(u16x4*)&dst[(size_t)(n0 + r) * K + k0 + c0] = o;
  } else {
    if (!useAW) return;
    size_t base = ((size_t)(bid - 10240) * 256 + tid) * 8;
    if (base < (size_t)NV_ * NV_) {
      float4 a0 = *(const float4*)&A[base];
      float4 a1 = *(const float4*)&A[base + 4];
      float4 w0 = *(const float4*)&W[base];
      float4 w1v = *(const float4*)&W[base + 4];
      u16x8 o;
      o[0] = f2bf(a0.x * w0.x * 10.f); o[1] = f2bf(a0.y * w0.y * 10.f);
      o[2] = f2bf(a0.z * w0.z * 10.f); o[3] = f2bf(a0.w * w0.w * 10.f);
      o[4] = f2bf(a1.x * w1v.x * 10.f); o[5] = f2bf(a1.y * w1v.y * 10.f);
      o[6] = f2bf(a1.z * w1v.z * 10.f); o[7] = f2bf(a1.w * w1v.w * 10.f);
      *(u16x8*)&AWb[base] = o;
    }
  }
}

// ---------------- kernel B: sim | fused QKV GEMM, INTERLEAVED block IDs ----------
// 9728 blocks = 512 groups x (16 sim + 3 qkv); sim stages 10KB bf16 AW row.
__global__ __launch_bounds__(256) void simqkv_kernel(
    const int* __restrict__ vx, const float* __restrict__ A,
    const float* __restrict__ W, const unsigned short* __restrict__ AWb,
    float* __restrict__ sim, const unsigned short* __restrict__ enc0b,
    const unsigned short* __restrict__ BT, unsigned short* __restrict__ QKV,
    int useAW) {
  __shared__ __attribute__((aligned(16))) char arena[28672];
  int bid = blockIdx.x;
  int tid = threadIdx.x;
  int g = bid / 19, rr = bid % 19;
  if (rr < 16) {
    // ---- sim job g*16+rr ----
    int job = g * 16 + rr;
    int i = job & 2047;
    int b = job >> 11;
    int vi = vx[b * S_ + i];
    float* out = sim + ((size_t)(b * S_ + i)) * S_;
    if (vi == 0) {
      for (int j = tid * 4; j < S_; j += 1024)
        *(float4*)&out[j] = (float4){0.f, 0.f, 0.f, 0.f};
      return;
    }
    if (useAW) {
      unsigned short* AWr = (unsigned short*)arena;  // 10000 B used
      int w = tid >> 6, l = tid & 63;
      const char* AWbase = (const char*)(AWb + (size_t)(vi - 1) * NV_);
      #pragma unroll
      for (int it = 0; it < 3; ++it) {
        int seg = it * 4 + w;          // wave-uniform LDS segment (1 KB)
        int chunk = seg * 64 + l;      // per-lane 16B chunk
        if (chunk < 625)
          gload16(AWbase + (size_t)chunk * 16, (char*)AWr + seg * 1024);
      }
      asm volatile("s_waitcnt vmcnt(0)" ::: "memory");
      __syncthreads();
      for (int j = tid * 4; j < S_; j += 1024) {
        int4 vj = *(const int4*)&vx[b * S_ + j];
        float4 o;
        o.x = vj.x ? bf2f(AWr[vj.x - 1]) : 0.f;
        o.y = vj.y ? bf2f(AWr[vj.y - 1]) : 0.f;
        o.z = vj.z ? bf2f(AWr[vj.z - 1]) : 0.f;
        o.w = vj.w ? bf2f(AWr[vj.w - 1]) : 0.f;
        *(float4*)&out[j] = o;
      }
    } else {
      // fallback: direct global gather (correct, slower)
      const float* Arow = A + (size_t)(vi - 1) * NV_;
      const float* Wrow = W + (size_t)(vi - 1) * NV_;
      for (int j = tid * 4; j < S_; j += 1024) {
        int4 vj = *(const int4*)&vx[b * S_ + j];
        float4 o;
        o.x = vj.x ? Arow[vj.x - 1] * Wrow[vj.x - 1] * 10.0f : 0.f;
        o.y = vj.y ? Arow[vj.y - 1] * Wrow[vj.y - 1] * 10.0f : 0.f;
        o.z = vj.z ? Arow[vj.z - 1] * Wrow[vj.z - 1] * 10.0f : 0.f;
        o.w = vj.w ? Arow[vj.w - 1] * Wrow[vj.w - 1] * 10.0f : 0.f;
        *(float4*)&out[j] = o;
      }
    }
  } else {
    // ---- QKV GEMM job g*3+(rr-16): M=8192, N=1536, K=512; MT=64 ----
    unsigned short* As = (unsigned short*)arena;            // [64][72]
    unsigned short* Bs = (unsigned short*)(arena + 9216);   // [128][72]
    int qb = g * 3 + (rr - 16);      // 0..1535
    int bx = qb % 12, by = qb / 12;
    int w = tid >> 6, l = tid & 63;
    int l16 = l & 15, lh = l >> 4;
    int row0 = by * 64, col0 = bx * 128;
    int ra = tid >> 1, ha = (tid & 1) * 32;
    int ra2 = tid >> 2, ha2 = (tid & 3) * 16;
    f32x4 acc[4][2];
    #pragma unroll
    for (int m = 0; m < 4; ++m)
      #pragma unroll
      for (int n = 0; n < 2; ++n) acc[m][n] = (f32x4){0.f, 0.f, 0.f, 0.f};

    for (int k0 = 0; k0 < 512; k0 += 64) {
      __syncthreads();
      {
        const unsigned short* sa = &enc0b[(size_t)(row0 + ra2) * 512 + k0 + ha2];
        uint4 a0 = *(const uint4*)(sa);
        uint4 a1 = *(const uint4*)(sa + 8);
        *(uint4*)&As[ra2 * 72 + ha2 + 0] = a0;
        *(uint4*)&As[ra2 * 72 + ha2 + 8] = a1;
        const unsigned short* sb = &BT[(size_t)(col0 + ra) * 512 + k0 + ha];
        uint4 b0 = *(const uint4*)(sb);
        uint4 b1 = *(const uint4*)(sb + 8);
        uint4 b2 = *(const uint4*)(sb + 16);
        uint4 b3 = *(const uint4*)(sb + 24);
        *(uint4*)&Bs[ra * 72 + ha + 0] = b0;
        *(uint4*)&Bs[ra * 72 + ha + 8] = b1;
        *(uint4*)&Bs[ra * 72 + ha + 16] = b2;
        *(uint4*)&Bs[ra * 72 + ha + 24] = b3;
      }
      __syncthreads();
      #pragma unroll
      for (int kc = 0; kc < 2; ++kc) {
        bf16x8 af[4], bfr[2];
        #pragma unroll
        for (int m = 0; m < 4; ++m)
          af[m] = *(bf16x8*)&As[(m * 16 + l16) * 72 + kc * 32 + lh * 8];
        #pragma unroll
        for (int n = 0; n < 2; ++n)
          bfr[n] = *(bf16x8*)&Bs[(w * 32 + n * 16 + l16) * 72 + kc * 32 + lh * 8];
        #pragma unroll
        for (int m = 0; m < 4; ++m)
          #pragma unroll
          for (int n = 0; n < 2; ++n)
            acc[m][n] = __builtin_amdgcn_mfma_f32_16x16x32_bf16(af[m], bfr[n], acc[m][n], 0, 0, 0);
      }
    }
    #pragma unroll
    for (int m = 0; m < 4; ++m) {
      #pragma unroll
      for (int r = 0; r < 4; ++r) {
        int row = row0 + m * 16 + lh * 4 + r;
        #pragma unroll
        for (int n = 0; n < 2; ++n) {
          int colg = col0 + w * 32 + n * 16 + l16;
          float v = acc[m][n][r];
          int which = colg >> 9;       // 0=Q 1=K 2=V
          int cl = colg & 511;
          int b = row >> 11, s = row & 2047;
          int h = cl >> 7, d = cl & 127;
          unsigned short* base = QKV + (size_t)which * 4194304;
          if (which < 2)
            base[((size_t)((b * 4 + h) * 2048 + s)) * 128 + d] = f2bf(v);
          else
            base[((size_t)((b * 4 + h) * 128 + d)) * 2048 + s] = f2bf(v);
        }
      }
    }
  }
}

// ---------------- bf16 MFMA GEMM: C = A[M,K] @ BT[N,K]^T (+bias)(+relu) ----------
// OMODE: 0 = f32 [M][N]; 1 = bf16 [M][N]
template <int OMODE, bool RELU, int MT = 128>
__global__ __launch_bounds__(256) void gemm_bf16_kernel(
    const unsigned short* __restrict__ A, const unsigned short* __restrict__ BT,
    const float* __restrict__ bias, void* __restrict__ C,
    int M, int N, int K) {
  __shared__ __attribute__((aligned(16))) unsigned short As[MT][72];
  __shared__ __attribute__((aligned(16))) unsigned short Bs[128][72];
  int tid = threadIdx.x;
  int w = tid >> 6, l = tid & 63;
  int l16 = l & 15, lh = l >> 4;
  const int NFR = (MT == 128) ? 4 : 2;
  int wr = (MT == 128) ? (w >> 1) : 0;
  int wc = (MT == 128) ? (w & 1) : w;
  int row0 = blockIdx.y * MT, col0 = blockIdx.x * 128;
  int ra = tid >> 1, ha = (tid & 1) * 32;
  f32x4 acc[4][4];
  #pragma unroll
  for (int m = 0; m < 4; ++m)
    #pragma unroll
    for (int n = 0; n < NFR; ++n) acc[m][n] = (f32x4){0.f, 0.f, 0.f, 0.f};

  for (int k0 = 0; k0 < K; k0 += 64) {
    __syncthreads();
    if (MT == 128) {
      const unsigned short* sa = &A[(size_t)(row0 + ra) * K + k0 + ha];
      uint4 a0 = *(const uint4*)(sa);
      uint4 a1 = *(const uint4*)(sa + 8);
      uint4 a2 = *(const uint4*)(sa + 16);
      uint4 a3 = *(const uint4*)(sa + 24);
      *(uint4*)&As[ra][ha + 0] = a0;
      *(uint4*)&As[ra][ha + 8] = a1;
      *(uint4*)&As[ra][ha + 16] = a2;
      *(uint4*)&As[ra][ha + 24] = a3;
    } else {
      int ra2 = tid >> 2, ha2 = (tid & 3) * 16;
      const unsigned short* sa = &A[(size_t)(row0 + ra2) * K + k0 + ha2];
      uint4 a0 = *(const uint4*)(sa);
      uint4 a1 = *(const uint4*)(sa + 8);
      *(uint4*)&As[ra2][ha2 + 0] = a0;
      *(uint4*)&As[ra2][ha2 + 8] = a1;
    }
    {
      const unsigned short* sb = &BT[(size_t)(col0 + ra) * K + k0 + ha];
      uint4 b0 = *(const uint4*)(sb);
      uint4 b1 = *(const uint4*)(sb + 8);
      uint4 b2 = *(const uint4*)(sb + 16);
      uint4 b3 = *(const uint4*)(sb + 24);
      *(uint4*)&Bs[ra][ha + 0] = b0;
      *(uint4*)&Bs[ra][ha + 8] = b1;
      *(uint4*)&Bs[ra][ha + 16] = b2;
      *(uint4*)&Bs[ra][ha + 24] = b3;
    }
    __syncthreads();
    #pragma unroll
    for (int kc = 0; kc < 2; ++kc) {
      bf16x8 af[4], bfr[4];
      #pragma unroll
      for (int m = 0; m < 4; ++m)
        af[m] = *(bf16x8*)&As[wr * 64 + m * 16 + l16][kc * 32 + lh * 8];
      #pragma unroll
      for (int n = 0; n < NFR; ++n)
        bfr[n] = *(bf16x8*)&Bs[wc * (16 * NFR) + n * 16 + l16][kc * 32 + lh * 8];
      #pragma unroll
      for (int m = 0; m < 4; ++m)
        #pragma unroll
        for (int n = 0; n < NFR; ++n)
          acc[m][n] = __builtin_amdgcn_mfma_f32_16x16x32_bf16(af[m], bfr[n], acc[m][n], 0, 0, 0);
    }
  }
  #pragma unroll
  for (int m = 0; m < 4; ++m) {
    #pragma unroll
    for (int r = 0; r < 4; ++r) {
      int row = row0 + wr * 64 + m * 16 + lh * 4 + r;
      #pragma unroll
      for (int n = 0; n < NFR; ++n) {
        int colg = col0 + wc * (16 * NFR) + n * 16 + l16;
        float v = acc[m][n][r];
        if (bias) v += bias[colg];
        if (RELU) v = fmaxf(v, 0.f);
        if (OMODE == 0) {
          ((float*)C)[(size_t)row * N + colg] = v;
        } else {
          ((unsigned short*)C)[(size_t)row * N + colg] = f2bf(v);
        }
      }
    }
  }
}

// ---------------- MFMA flash attention: async gload_lds staging, swizzled tiles ----
__global__ __launch_bounds__(256) void attn_mfma_kernel(
    const unsigned short* __restrict__ Qb, const unsigned short* __restrict__ Kb,
    const unsigned short* __restrict__ Vt, const float* __restrict__ sim,
    const float* __restrict__ npm, unsigned short* __restrict__ Op0,
    unsigned short* __restrict__ Op1, float2* __restrict__ ml0,
    float2* __restrict__ ml1) {
  __shared__ __attribute__((aligned(16))) char KsL[2][16384];   // [64][128] bf16
  __shared__ __attribute__((aligned(16))) char VtsL[2][16384];  // [128][64] bf16
  __shared__ __attribute__((aligned(16))) unsigned short Pl[4][16][72];
  int bid = blockIdx.x;          // 0..511
  int xcd = bid & 7;
  int j0 = bid >> 3;             // 0..63
  int bh = xcd * 2 + (j0 & 1);
  int jj = j0 >> 1;              // 0..31
  int pair = jj & 15;
  int half = jj >> 4;
  int b = bh >> 2;
  int tid = threadIdx.x;
  int w = tid >> 6, l = tid & 63;
  int l16 = l & 15, lh = l >> 4;
  unsigned short* Op = half ? Op1 : Op0;
  float2* ml = half ? ml1 : ml0;

  const char* KbB = (const char*)Kb + (size_t)bh * 2048 * 256;
  const char* VtB = (const char*)Vt + (size_t)bh * 128 * 4096;
  int krow[4], kcol[4], vrow4[4], vcol[4];
  #pragma unroll
  for (int j = 0; j < 4; ++j) {
    int i = w * 4 + j;
    krow[j] = i * 4 + (l >> 4);
    kcol[j] = ((l & 15) * 16) ^ ((krow[j] & 7) << 4);
    vrow4[j] = i * 8 + (l >> 3);
    vcol[j] = ((l & 7) * 16) ^ ((vrow4[j] & 7) << 4);
  }
  int xr = (l16 & 7) << 4;

  #pragma unroll 1
  for (int pj = 0; pj < 2; ++pj) {
    int qt = pj ? 31 - pair : pair;
    int nst = qt + 1;
    int c0 = (nst + 1) >> 1;
    int t0 = half ? c0 : 0;
    int cnt = half ? nst - c0 : c0;
    int q0 = qt * 64 + w * 16;
    int qg = q0 + l16;

    bf16x8 qf[4];
    const unsigned short* Qrow = Qb + ((size_t)(bh * 2048 + qg)) * 128;
    #pragma unroll
    for (int kq = 0; kq < 4; ++kq)
      qf[kq] = *(const bf16x8*)&Qrow[kq * 32 + lh * 8];

    float m_l = -INFINITY, l_l = 0.f;
    f32x4 o_acc[8];
    #pragma unroll
    for (int c = 0; c < 8; ++c) o_acc[c] = (f32x4){0.f, 0.f, 0.f, 0.f};

    const float* simrow = sim + ((size_t)(b * 2048) + qg) * 2048;
    const float* mrow = npm + b * 2048;

    if (cnt > 0) {
      #pragma unroll
      for (int j = 0; j < 4; ++j) {
        int i = w * 4 + j;
        gload16(KbB + (size_t)(t0 * 64 + krow[j]) * 256 + kcol[j],
                &KsL[0][i * 1024]);
        gload16(VtB + (size_t)vrow4[j] * 4096 + (size_t)(t0 * 64) * 2 + vcol[j],
                &VtsL[0][i * 1024]);
      }
      asm volatile("s_waitcnt vmcnt(0)" ::: "memory");
      __syncthreads();

      #pragma unroll 1
      for (int ti = 0; ti < cnt; ++ti) {
        int cur = ti & 1;
        int kv0 = (t0 + ti) * 64;
        if (ti + 1 < cnt) {
          int kvn = kv0 + 64;
          #pragma unroll
          for (int j = 0; j < 4; ++j) {
            int i = w * 4 + j;
            gload16(KbB + (size_t)(kvn + krow[j]) * 256 + kcol[j],
                    &KsL[cur ^ 1][i * 1024]);
            gload16(VtB + (size_t)vrow4[j] * 4096 + (size_t)kvn * 2 + vcol[j],
                    &VtsL[cur ^ 1][i * 1024]);
          }
        }
        const char* Kbase = KsL[cur];
        f32x4 sc[4];
        #pragma unroll
        for (int tt = 0; tt < 4; ++tt) {
          sc[tt] = (f32x4){0.f, 0.f, 0.f, 0.f};
          const char* Krow = Kbase + (tt * 16 + l16) * 256;
          #pragma unroll
          for (int kq = 0; kq < 4; ++kq) {
            bf16x8 kf = *(const bf16x8*)(Krow + ((kq * 64 + lh * 16) ^ xr));
            sc[tt] = __builtin_amdgcn_mfma_f32_16x16x32_bf16(kf, qf[kq], sc[tt], 0, 0, 0);
          }
        }
        float4 sim4[4], mk4[4];
        #pragma unroll
        for (int tt = 0; tt < 4; ++tt) {
          sim4[tt] = *(const float4*)&simrow[kv0 + tt * 16 + lh * 4];
          mk4[tt] = *(const float4*)&mrow[kv0 + tt * 16 + lh * 4];
        }
        float sv[4][4];
        #pragma unroll
        for (int tt = 0; tt < 4; ++tt) {
          #pragma unroll
          for (int r = 0; r < 4; ++r) {
            int kvg = kv0 + tt * 16 + lh * 4 + r;
            float mkr = r == 0 ? mk4[tt].x : r == 1 ? mk4[tt].y
                      : r == 2 ? mk4[tt].z : mk4[tt].w;
            float smr = r == 0 ? sim4[tt].x : r == 1 ? sim4[tt].y
                      : r == 2 ? sim4[tt].z : sim4[tt].w;
            bool valid = (kvg <= qg) && (mkr != 0.f);
            sv[tt][r] = valid ? sc[tt][r] * 0.08838834764831845f + smr : -1e9f;
          }
        }
        float mx = sv[0][0];
        #pragma unroll
        for (int tt = 0; tt < 4; ++tt)
          #pragma unroll
          for (int r = 0; r < 4; ++r) mx = fmaxf(mx, sv[tt][r]);
        mx = fmaxf(mx, __shfl_xor(mx, 16));
        mx = fmaxf(mx, __shfl_xor(mx, 32));
        float mn = fmaxf(m_l, mx);
        float alpha = __expf(m_l - mn);
        m_l = mn;
        float ts = 0.f;
        #pragma unroll
        for (int tt = 0; tt < 4; ++tt)
          #pragma unroll
          for (int r = 0; r < 4; ++r) {
            float ppv = __expf(sv[tt][r] - mn);
            sv[tt][r] = ppv;
            ts += ppv;
          }
        ts += __shfl_xor(ts, 16);
        ts += __shfl_xor(ts, 32);
        l_l = l_l * alpha + ts;
        #pragma unroll
        for (int tt = 0; tt < 4; ++tt) {
          u16x4 pw;
          pw[0] = f2bf(sv[tt][0]); pw[1] = f2bf(sv[tt][1]);
          pw[2] = f2bf(sv[tt][2]); pw[3] = f2bf(sv[tt][3]);
          *(u16x4*)&Pl[w][l16][tt * 16 + lh * 4] = pw;
        }
        float al[4];
        #pragma unroll
        for (int r = 0; r < 4; ++r) al[r] = __shfl(alpha, lh * 4 + r);
        #pragma unroll
        for (int c = 0; c < 8; ++c)
          #pragma unroll
          for (int r = 0; r < 4; ++r) o_acc[c][r] *= al[r];
        const char* Vbase = VtsL[cur];
        #pragma unroll
        for (int kf2 = 0; kf2 < 2; ++kf2) {
          bf16x8 pa = *(bf16x8*)&Pl[w][l16][kf2 * 32 + lh * 8];
          #pragma unroll
          for (int c = 0; c < 8; ++c) {
            bf16x8 vf = *(const bf16x8*)(Vbase + (c * 16 + l16) * 128 +
                                         ((kf2 * 64 + lh * 16) ^ xr));
            o_acc[c] = __builtin_amdgcn_mfma_f32_16x16x32_bf16(pa, vf, o_acc[c], 0, 0, 0);
          }
        }
        asm volatile("s_waitcnt vmcnt(0)" ::: "memory");
        __syncthreads();
      }
    }
    #pragma unroll
    for (int r = 0; r < 4; ++r) {
      int qgr = q0 + lh * 4 + r;
      unsigned short* op = Op + ((size_t)(bh * 2048 + qgr)) * 128;
      #pragma unroll
      for (int c = 0; c < 8; ++c) op[c * 16 + l16] = f2bf(o_acc[c][r]);
    }
    if (lh == 0) {
      float2 v; v.x = m_l; v.y = l_l;
      ml[bh * 2048 + q0 + l16] = v;
    }
    __syncthreads();
  }
}

// ---------------- combine partials -> final attn output (token-major bf16) ------
__global__ __launch_bounds__(256) void attn_combine_kernel(
    const unsigned short* __restrict__ Op0, const unsigned short* __restrict__ Op1,
    const float2* __restrict__ ml0, const float2* __restrict__ ml1,
    unsigned short* __restrict__ Of) {
  int idx = blockIdx.x * 256 + threadIdx.x;
  int row = idx >> 4;
  int d0 = (idx & 15) * 8;
  float2 a = ml0[row], c2 = ml1[row];
  float m = fmaxf(a.x, c2.x);
  float e1 = __expf(a.x - m), e2 = __expf(c2.x - m);
  float inv = 1.f / (e1 * a.y + e2 * c2.y);
  u16x8 o1 = *(const u16x8*)&Op0[(size_t)row * 128 + d0];
  u16x8 o2 = *(const u16x8*)&Op1[(size_t)row * 128 + d0];
  int bh = row >> 11, q = row & 2047;
  int b = bh >> 2, h = bh & 3;
  unsigned short* dst = Of + ((size_t)(b * 2048 + q)) * 512 + h * 128 + d0;
  u16x8 o;
  #pragma unroll
  for (int j = 0; j < 8; ++j)
    o[j] = f2bf((bf2f(o1[j]) * e1 + bf2f(o2[j]) * e2) * inv);
  *(u16x8*)dst = o;
}

// ---------------- layernorm (+ optional bf16 copy) ----------------
__global__ __launch_bounds__(256) void ln_kernel(
    const float* __restrict__ x, const float* __restrict__ res,
    const float* __restrict__ g, const float* __restrict__ bta,
    const float* __restrict__ npm, float* __restrict__ out,
    unsigned short* __restrict__ out16) {
  __shared__ float ssum[4], ssq[4];
  int row = blockIdx.x;
  int tid = threadIdx.x;
  size_t base = (size_t)row * DM_;
  float v0 = x[base + tid] + res[base + tid];
  float v1 = x[base + tid + 256] + res[base + tid + 256];
  float sum = v0 + v1, sq = v0 * v0 + v1 * v1;
  #pragma unroll
  for (int off = 32; off >= 1; off >>= 1) {
    sum += __shfl_down(sum, off);
    sq += __shfl_down(sq, off);
  }
  int wid = tid >> 6, lane = tid & 63;
  if (lane == 0) { ssum[wid] = sum; ssq[wid] = sq; }
  __syncthreads();
  sum = ssum[0] + ssum[1] + ssum[2] + ssum[3];
  sq = ssq[0] + ssq[1] + ssq[2] + ssq[3];
  float mean = sum * (1.f / DM_);
  float var = sq * (1.f / DM_) - mean * mean;
  float rs = rsqrtf(var + 1e-5f);
  float mask = npm[row];
  float o0 = ((v0 - mean) * rs * g[tid] + bta[tid]) * mask;
  float o1 = ((v1 - mean) * rs * g[tid + 256] + bta[tid + 256]) * mask;
  out[base + tid] = o0;
  out[base + tid + 256] = o1;
  if (out16) {
    out16[base + tid] = f2bf(o0);
    out16[base + tid + 256] = f2bf(o1);
  }
}

extern "C" void kernel_launch(void* const* d_in, const int* in_sizes, int n_in,
                              void* d_out, int out_size, void* d_ws,
                              size_t ws_size, hipStream_t stream) {
  const int* et = (const int*)d_in[0];
  const int* vx = (const int*)d_in[1];
  const float* tmv = (const float*)d_in[2];
  const float* npm = (const float*)d_in[3];
  const float* Amat = (const float*)d_in[4];
  const float* Wmat = (const float*)d_in[5];
  const float* eemb = (const float*)d_in[6];
  const float* vemb = (const float*)d_in[7];
  const float* Wq = (const float*)d_in[8];
  const float* Wk = (const float*)d_in[9];
  const float* Wv = (const float*)d_in[10];
  const float* Wo = (const float*)d_in[11];
  const float* bo = (const float*)d_in[12];
  const float* ln1g = (const float*)d_in[13];
  const float* ln1b = (const float*)d_in[14];
  const float* w1 = (const float*)d_in[15];
  const float* b1 = (const float*)d_in[16];
  const float* w2 = (const float*)d_in[17];
  const float* b2 = (const float*)d_in[18];
  const float* ln2g = (const float*)d_in[19];
  const float* ln2b = (const float*)d_in[20];

  float* out = (float*)d_out;
  float* enc_out = out;
  float* sim_out = out + (size_t)B_ * S_ * DM_;

  const size_t MB = 1ull << 20;
  char* wsb = (char*)d_ws;
  float* enc0 = (float*)(wsb + 0);                             // 0-16: live to LN1
  unsigned short* enc0b = (unsigned short*)(wsb + 16 * MB);    // 16-24
  unsigned short* WqT = (unsigned short*)(wsb + 24 * MB);      // 24-28: weights
  unsigned short* WkT = WqT + 512 * 512;
  unsigned short* WvT = WkT + 512 * 512;
  unsigned short* WoT = WvT + 512 * 512;
  unsigned short* w1T = WoT + 512 * 512;
  unsigned short* w2T = w1T + 1024 * 512;
  unsigned short* Qb16 = (unsigned short*)(wsb + 28 * MB);     // 28-36
  unsigned short* Kb16 = (unsigned short*)(wsb + 36 * MB);     // 36-44
  unsigned short* Vt16 = (unsigned short*)(wsb + 44 * MB);     // 44-52
  unsigned short* Op0 = (unsigned short*)(wsb + 52 * MB);      // 52-60 partial half0
  unsigned short* Op1 = enc0b;                                 // 16-24 partial half1
  float2* ml0 = (float2*)(wsb + 60 * MB);                      // 60-60.25
  float2* ml1 = ml0 + 32768;                                   // 60.25-60.5
  unsigned short* Of16 = Qb16;           // 28-36 (Q dead after attn)
  float* OP = (float*)(wsb + 88 * MB);   // 88-104
  float* enc1 = OP;                      // LN1 in-place
  unsigned short* enc1b = enc0b;         // 16-24 (Op1 dead after combine)
  unsigned short* hid = Kb16;            // 36-52 (K,V dead after attn)
  float* fbuf = (float*)(wsb + 52 * MB); // 52-68 (Op0/ml dead after combine)
  unsigned short* AWb = (unsigned short*)(wsb + 104 * MB);     // 104-154: bf16 AW
  int useAW = (ws_size >= 104 * MB + (size_t)NV_ * NV_ * 2) ? 1 : 0;

  int M = B_ * S_;

  int ewBlocks = 10240 + (useAW ? 12208 : 0);
  ew_kernel<<<dim3(ewBlocks), dim3(256), 0, stream>>>(
      et, vx, tmv, npm, eemb, vemb, Wq, Wk, Wv, Wo, w1, w2, Amat, Wmat,
      enc0, enc0b, WqT, WkT, WvT, WoT, w1T, w2T, AWb, useAW);

  simqkv_kernel<<<dim3(9728), dim3(256), 0, stream>>>(
      vx, Amat, Wmat, AWb, sim_out, enc0b, WqT, Qb16, useAW);

  attn_mfma_kernel<<<dim3(512), dim3(256), 0, stream>>>(
      Qb16, Kb16, Vt16, sim_out, npm, Op0, Op1, ml0, ml1);
  attn_combine_kernel<<<dim3(2048), dim3(256), 0, stream>>>(
      Op0, Op1, ml0, ml1, Of16);

  gemm_bf16_kernel<0, false, 64><<<dim3(4, 128), dim3(256), 0, stream>>>(
      Of16, WoT, bo, OP, M, DM_, DM_);
  ln_kernel<<<dim3(M), dim3(256), 0, stream>>>(OP, enc0, ln1g, ln1b, npm, enc1,
                                               enc1b);

  gemm_bf16_kernel<1, true, 64><<<dim3(8, 128), dim3(256), 0, stream>>>(
      enc1b, w1T, b1, hid, M, DI_, DM_);
  gemm_bf16_kernel<0, false, 64><<<dim3(4, 128), dim3(256), 0, stream>>>(
      hid, w2T, b2, fbuf, M, DM_, DI_);
  ln_kernel<<<dim3(M), dim3(256), 0, stream>>>(fbuf, enc1, ln2g, ln2b, npm,
                                               enc_out, nullptr);
}

// Round 24
// 279.189 us; speedup vs baseline: 1.0218x; 1.0218x over previous
//
#include <hip/hip_runtime.h>
#include <hip/hip_bf16.h>

#define B_ 4
#define S_ 2048
#define DM_ 512
#define H_ 4
#define DK_ 128
#define DI_ 1024
#define NV_ 5000

typedef __attribute__((ext_vector_type(8))) short bf16x8;
typedef __attribute__((ext_vector_type(8))) unsigned short u16x8;
typedef __attribute__((ext_vector_type(4))) unsigned short u16x4;
typedef __attribute__((ext_vector_type(4))) float f32x4;

__device__ inline unsigned short f2bf(float x) {
  unsigned int u = __float_as_uint(x);
  unsigned int r = (u + 0x7fffu + ((u >> 16) & 1u)) >> 16;
  return (unsigned short)r;
}
__device__ inline float bf2f(unsigned short u) {
  return __uint_as_float(((unsigned int)u) << 16);
}
__device__ inline void gload16(const void* g, void* l) {
  __builtin_amdgcn_global_load_lds(
      (const __attribute__((address_space(1))) void*)g,
      (__attribute__((address_space(3))) void*)l, 16, 0, 0);
}

// ---------------- dedicated AW = bf16(A*W*10) streaming build ----------------
// 1024 fat grid-stride blocks; pure stream: 200 MB read + 50 MB write.
__global__ __launch_bounds__(256) void aw_kernel(
    const float* __restrict__ A, const float* __restrict__ W,
    unsigned short* __restrict__ AWb) {
  const size_t total = (size_t)NV_ * NV_;  // 25,000,000 (divisible by 8)
  size_t stride = (size_t)gridDim.x * 256 * 8;
  for (size_t base = ((size_t)blockIdx.x * 256 + threadIdx.x) * 8;
       base < total; base += stride) {
    float4 a0 = *(const float4*)&A[base];
    float4 a1 = *(const float4*)&A[base + 4];
    float4 w0 = *(const float4*)&W[base];
    float4 w1v = *(const float4*)&W[base + 4];
    u16x8 o;
    o[0] = f2bf(a0.x * w0.x * 10.f); o[1] = f2bf(a0.y * w0.y * 10.f);
    o[2] = f2bf(a0.z * w0.z * 10.f); o[3] = f2bf(a0.w * w0.w * 10.f);
    o[4] = f2bf(a1.x * w1v.x * 10.f); o[5] = f2bf(a1.y * w1v.y * 10.f);
    o[6] = f2bf(a1.z * w1v.z * 10.f); o[7] = f2bf(a1.w * w1v.w * 10.f);
    *(u16x8*)&AWb[base] = o;
  }
}

// ---------------- kernel A: embed (0-8191) | wt (8192-10239) ----------------
__global__ __launch_bounds__(256) void ew_kernel(
    const int* __restrict__ et, const int* __restrict__ vx,
    const float* __restrict__ tmv, const float* __restrict__ npm,
    const float* __restrict__ eemb, const float* __restrict__ vemb,
    const float* __restrict__ Wq, const float* __restrict__ Wk,
    const float* __restrict__ Wv, const float* __restrict__ Wo,
    const float* __restrict__ w1, const float* __restrict__ w2,
    float* __restrict__ enc0, unsigned short* __restrict__ enc0b,
    unsigned short* __restrict__ WqT, unsigned short* __restrict__ WkT,
    unsigned short* __restrict__ WvT, unsigned short* __restrict__ WoT,
    unsigned short* __restrict__ w1T, unsigned short* __restrict__ w2T) {
  __shared__ unsigned short T[32][40];
  int bid = blockIdx.x;
  int tid = threadIdx.x;
  if (bid < 8192) {
    int row = bid;
    int t = et[row], v = vx[row];
    float time = tmv[row], mask = npm[row];
    #pragma unroll
    for (int k = 0; k < 2; ++k) {
      int dd = tid + k * 256;
      float pvinv = __expf((float)(dd & ~1) * -0.017988946039015984f);
      float r = time * pvinv;
      float tem = (((dd & 1) == 0) ? sinf(r) : cosf(r)) * mask;
      float val = eemb[(size_t)t * DM_ + dd] + vemb[(size_t)v * DM_ + dd] + tem;
      enc0[(size_t)row * DM_ + dd] = val;
      enc0b[(size_t)row * DM_ + dd] = f2bf(val);
    }
  } else {
    int wb = bid - 8192;
    const float* src; unsigned short* dst; int K, N, lid;
    if (wb < 256)       { src = Wq; dst = WqT; K = 512;  N = 512;  lid = wb; }
    else if (wb < 512)  { src = Wk; dst = WkT; K = 512;  N = 512;  lid = wb - 256; }
    else if (wb < 768)  { src = Wv; dst = WvT; K = 512;  N = 512;  lid = wb - 512; }
    else if (wb < 1024) { src = Wo; dst = WoT; K = 512;  N = 512;  lid = wb - 768; }
    else if (wb < 1536) { src = w1; dst = w1T; K = 512;  N = 1024; lid = wb - 1024; }
    else                { src = w2; dst = w2T; K = 1024; N = 512;  lid = wb - 1536; }
    int nt = N / 32;
    int n0 = (lid % nt) * 32, k0 = (lid / nt) * 32;
    int r = tid >> 3, c0 = (tid & 7) * 4;
    float4 v = *(const float4*)&src[(size_t)(k0 + r) * N + n0 + c0];
    T[r][c0 + 0] = f2bf(v.x);
    T[r][c0 + 1] = f2bf(v.y);
    T[r][c0 + 2] = f2bf(v.z);
    T[r][c0 + 3] = f2bf(v.w);
    __syncthreads();
    u16x4 o;
    o[0] = T[c0 + 0][r]; o[1] = T[c0 + 1][r];
    o[2] = T[c0 + 2][r]; o[3] = T[c0 + 3][r];
    *(u16x4*)&dst[(size_t)(n0 + r) * K + k0 + c0] = o;
  }
}

// ---------------- kernel B: sim | fused QKV GEMM, INTERLEAVED block IDs ----------
// 9728 blocks = 512 groups x (16 sim + 3 qkv); sim stages 10KB bf16 AW row.
__global__ __launch_bounds__(256) void simqkv_kernel(
    const int* __restrict__ vx, const float* __restrict__ A,
    const float* __restrict__ W, const unsigned short* __restrict__ AWb,
    float* __restrict__ sim, const unsigned short* __restrict__ enc0b,
    const unsigned short* __restrict__ BT, unsigned short* __restrict__ QKV,
    int useAW) {
  __shared__ __attribute__((aligned(16))) char arena[28672];
  int bid = blockIdx.x;
  int tid = threadIdx.x;
  int g = bid / 19, rr = bid % 19;
  if (rr < 16) {
    // ---- sim job g*16+rr ----
    int job = g * 16 + rr;
    int i = job & 2047;
    int b = job >> 11;
    int vi = vx[b * S_ + i];
    float* out = sim + ((size_t)(b * S_ + i)) * S_;
    if (vi == 0) {
      for (int j = tid * 4; j < S_; j += 1024)
        *(float4*)&out[j] = (float4){0.f, 0.f, 0.f, 0.f};
      return;
    }
    if (useAW) {
      unsigned short* AWr = (unsigned short*)arena;  // 10000 B used
      int w = tid >> 6, l = tid & 63;
      const char* AWbase = (const char*)(AWb + (size_t)(vi - 1) * NV_);
      #pragma unroll
      for (int it = 0; it < 3; ++it) {
        int seg = it * 4 + w;          // wave-uniform LDS segment (1 KB)
        int chunk = seg * 64 + l;      // per-lane 16B chunk
        if (chunk < 625)
          gload16(AWbase + (size_t)chunk * 16, (char*)AWr + seg * 1024);
      }
      asm volatile("s_waitcnt vmcnt(0)" ::: "memory");
      __syncthreads();
      for (int j = tid * 4; j < S_; j += 1024) {
        int4 vj = *(const int4*)&vx[b * S_ + j];
        float4 o;
        o.x = vj.x ? bf2f(AWr[vj.x - 1]) : 0.f;
        o.y = vj.y ? bf2f(AWr[vj.y - 1]) : 0.f;
        o.z = vj.z ? bf2f(AWr[vj.z - 1]) : 0.f;
        o.w = vj.w ? bf2f(AWr[vj.w - 1]) : 0.f;
        *(float4*)&out[j] = o;
      }
    } else {
      // fallback: direct global gather (correct, slower)
      const float* Arow = A + (size_t)(vi - 1) * NV_;
      const float* Wrow = W + (size_t)(vi - 1) * NV_;
      for (int j = tid * 4; j < S_; j += 1024) {
        int4 vj = *(const int4*)&vx[b * S_ + j];
        float4 o;
        o.x = vj.x ? Arow[vj.x - 1] * Wrow[vj.x - 1] * 10.0f : 0.f;
        o.y = vj.y ? Arow[vj.y - 1] * Wrow[vj.y - 1] * 10.0f : 0.f;
        o.z = vj.z ? Arow[vj.z - 1] * Wrow[vj.z - 1] * 10.0f : 0.f;
        o.w = vj.w ? Arow[vj.w - 1] * Wrow[vj.w - 1] * 10.0f : 0.f;
        *(float4*)&out[j] = o;
      }
    }
  } else {
    // ---- QKV GEMM job g*3+(rr-16): M=8192, N=1536, K=512; MT=64 ----
    unsigned short* As = (unsigned short*)arena;            // [64][72]
    unsigned short* Bs = (unsigned short*)(arena + 9216);   // [128][72]
    int qb = g * 3 + (rr - 16);      // 0..1535
    int bx = qb % 12, by = qb / 12;
    int w = tid >> 6, l = tid & 63;
    int l16 = l & 15, lh = l >> 4;
    int row0 = by * 64, col0 = bx * 128;
    int ra = tid >> 1, ha = (tid & 1) * 32;
    int ra2 = tid >> 2, ha2 = (tid & 3) * 16;
    f32x4 acc[4][2];
    #pragma unroll
    for (int m = 0; m < 4; ++m)
      #pragma unroll
      for (int n = 0; n < 2; ++n) acc[m][n] = (f32x4){0.f, 0.f, 0.f, 0.f};

    for (int k0 = 0; k0 < 512; k0 += 64) {
      __syncthreads();
      {
        const unsigned short* sa = &enc0b[(size_t)(row0 + ra2) * 512 + k0 + ha2];
        uint4 a0 = *(const uint4*)(sa);
        uint4 a1 = *(const uint4*)(sa + 8);
        *(uint4*)&As[ra2 * 72 + ha2 + 0] = a0;
        *(uint4*)&As[ra2 * 72 + ha2 + 8] = a1;
        const unsigned short* sb = &BT[(size_t)(col0 + ra) * 512 + k0 + ha];
        uint4 b0 = *(const uint4*)(sb);
        uint4 b1 = *(const uint4*)(sb + 8);
        uint4 b2 = *(const uint4*)(sb + 16);
        uint4 b3 = *(const uint4*)(sb + 24);
        *(uint4*)&Bs[ra * 72 + ha + 0] = b0;
        *(uint4*)&Bs[ra * 72 + ha + 8] = b1;
        *(uint4*)&Bs[ra * 72 + ha + 16] = b2;
        *(uint4*)&Bs[ra * 72 + ha + 24] = b3;
      }
      __syncthreads();
      #pragma unroll
      for (int kc = 0; kc < 2; ++kc) {
        bf16x8 af[4], bfr[2];
        #pragma unroll
        for (int m = 0; m < 4; ++m)
          af[m] = *(bf16x8*)&As[(m * 16 + l16) * 72 + kc * 32 + lh * 8];
        #pragma unroll
        for (int n = 0; n < 2; ++n)
          bfr[n] = *(bf16x8*)&Bs[(w * 32 + n * 16 + l16) * 72 + kc * 32 + lh * 8];
        #pragma unroll
        for (int m = 0; m < 4; ++m)
          #pragma unroll
          for (int n = 0; n < 2; ++n)
            acc[m][n] = __builtin_amdgcn_mfma_f32_16x16x32_bf16(af[m], bfr[n], acc[m][n], 0, 0, 0);
      }
    }
    #pragma unroll
    for (int m = 0; m < 4; ++m) {
      #pragma unroll
      for (int r = 0; r < 4; ++r) {
        int row = row0 + m * 16 + lh * 4 + r;
        #pragma unroll
        for (int n = 0; n < 2; ++n) {
          int colg = col0 + w * 32 + n * 16 + l16;
          float v = acc[m][n][r];
          int which = colg >> 9;       // 0=Q 1=K 2=V
          int cl = colg & 511;
          int b = row >> 11, s = row & 2047;
          int h = cl >> 7, d = cl & 127;
          unsigned short* base = QKV + (size_t)which * 4194304;
          if (which < 2)
            base[((size_t)((b * 4 + h) * 2048 + s)) * 128 + d] = f2bf(v);
          else
            base[((size_t)((b * 4 + h) * 128 + d)) * 2048 + s] = f2bf(v);
        }
      }
    }
  }
}

// ---------------- bf16 MFMA GEMM: C = A[M,K] @ BT[N,K]^T (+bias)(+relu) ----------
// OMODE: 0 = f32 [M][N]; 1 = bf16 [M][N]
template <int OMODE, bool RELU, int MT = 128>
__global__ __launch_bounds__(256) void gemm_bf16_kernel(
    const unsigned short* __restrict__ A, const unsigned short* __restrict__ BT,
    const float* __restrict__ bias, void* __restrict__ C,
    int M, int N, int K) {
  __shared__ __attribute__((aligned(16))) unsigned short As[MT][72];
  __shared__ __attribute__((aligned(16))) unsigned short Bs[128][72];
  int tid = threadIdx.x;
  int w = tid >> 6, l = tid & 63;
  int l16 = l & 15, lh = l >> 4;
  const int NFR = (MT == 128) ? 4 : 2;
  int wr = (MT == 128) ? (w >> 1) : 0;
  int wc = (MT == 128) ? (w & 1) : w;
  int row0 = blockIdx.y * MT, col0 = blockIdx.x * 128;
  int ra = tid >> 1, ha = (tid & 1) * 32;
  f32x4 acc[4][4];
  #pragma unroll
  for (int m = 0; m < 4; ++m)
    #pragma unroll
    for (int n = 0; n < NFR; ++n) acc[m][n] = (f32x4){0.f, 0.f, 0.f, 0.f};

  for (int k0 = 0; k0 < K; k0 += 64) {
    __syncthreads();
    if (MT == 128) {
      const unsigned short* sa = &A[(size_t)(row0 + ra) * K + k0 + ha];
      uint4 a0 = *(const uint4*)(sa);
      uint4 a1 = *(const uint4*)(sa + 8);
      uint4 a2 = *(const uint4*)(sa + 16);
      uint4 a3 = *(const uint4*)(sa + 24);
      *(uint4*)&As[ra][ha + 0] = a0;
      *(uint4*)&As[ra][ha + 8] = a1;
      *(uint4*)&As[ra][ha + 16] = a2;
      *(uint4*)&As[ra][ha + 24] = a3;
    } else {
      int ra2 = tid >> 2, ha2 = (tid & 3) * 16;
      const unsigned short* sa = &A[(size_t)(row0 + ra2) * K + k0 + ha2];
      uint4 a0 = *(const uint4*)(sa);
      uint4 a1 = *(const uint4*)(sa + 8);
      *(uint4*)&As[ra2][ha2 + 0] = a0;
      *(uint4*)&As[ra2][ha2 + 8] = a1;
    }
    {
      const unsigned short* sb = &BT[(size_t)(col0 + ra) * K + k0 + ha];
      uint4 b0 = *(const uint4*)(sb);
      uint4 b1 = *(const uint4*)(sb + 8);
      uint4 b2 = *(const uint4*)(sb + 16);
      uint4 b3 = *(const uint4*)(sb + 24);
      *(uint4*)&Bs[ra][ha + 0] = b0;
      *(uint4*)&Bs[ra][ha + 8] = b1;
      *(uint4*)&Bs[ra][ha + 16] = b2;
      *(uint4*)&Bs[ra][ha + 24] = b3;
    }
    __syncthreads();
    #pragma unroll
    for (int kc = 0; kc < 2; ++kc) {
      bf16x8 af[4], bfr[4];
      #pragma unroll
      for (int m = 0; m < 4; ++m)
        af[m] = *(bf16x8*)&As[wr * 64 + m * 16 + l16][kc * 32 + lh * 8];
      #pragma unroll
      for (int n = 0; n < NFR; ++n)
        bfr[n] = *(bf16x8*)&Bs[wc * (16 * NFR) + n * 16 + l16][kc * 32 + lh * 8];
      #pragma unroll
      for (int m = 0; m < 4; ++m)
        #pragma unroll
        for (int n = 0; n < NFR; ++n)
          acc[m][n] = __builtin_amdgcn_mfma_f32_16x16x32_bf16(af[m], bfr[n], acc[m][n], 0, 0, 0);
    }
  }
  #pragma unroll
  for (int m = 0; m < 4; ++m) {
    #pragma unroll
    for (int r = 0; r < 4; ++r) {
      int row = row0 + wr * 64 + m * 16 + lh * 4 + r;
      #pragma unroll
      for (int n = 0; n < NFR; ++n) {
        int colg = col0 + wc * (16 * NFR) + n * 16 + l16;
        float v = acc[m][n][r];
        if (bias) v += bias[colg];
        if (RELU) v = fmaxf(v, 0.f);
        if (OMODE == 0) {
          ((float*)C)[(size_t)row * N + colg] = v;
        } else {
          ((unsigned short*)C)[(size_t)row * N + colg] = f2bf(v);
        }
      }
    }
  }
}

// ---------------- MFMA flash attention: async gload_lds staging, swizzled tiles ----
__global__ __launch_bounds__(256) void attn_mfma_kernel(
    const unsigned short* __restrict__ Qb, const unsigned short* __restrict__ Kb,
    const unsigned short* __restrict__ Vt, const float* __restrict__ sim,
    const float* __restrict__ npm, unsigned short* __restrict__ Op0,
    unsigned short* __restrict__ Op1, float2* __restrict__ ml0,
    float2* __restrict__ ml1) {
  __shared__ __attribute__((aligned(16))) char KsL[2][16384];   // [64][128] bf16
  __shared__ __attribute__((aligned(16))) char VtsL[2][16384];  // [128][64] bf16
  __shared__ __attribute__((aligned(16))) unsigned short Pl[4][16][72];
  int bid = blockIdx.x;          // 0..511
  int xcd = bid & 7;
  int j0 = bid >> 3;             // 0..63
  int bh = xcd * 2 + (j0 & 1);
  int jj = j0 >> 1;              // 0..31
  int pair = jj & 15;
  int half = jj >> 4;
  int b = bh >> 2;
  int tid = threadIdx.x;
  int w = tid >> 6, l = tid & 63;
  int l16 = l & 15, lh = l >> 4;
  unsigned short* Op = half ? Op1 : Op0;
  float2* ml = half ? ml1 : ml0;

  const char* KbB = (const char*)Kb + (size_t)bh * 2048 * 256;
  const char* VtB = (const char*)Vt + (size_t)bh * 128 * 4096;
  int krow[4], kcol[4], vrow4[4], vcol[4];
  #pragma unroll
  for (int j = 0; j < 4; ++j) {
    int i = w * 4 + j;
    krow[j] = i * 4 + (l >> 4);
    kcol[j] = ((l & 15) * 16) ^ ((krow[j] & 7) << 4);
    vrow4[j] = i * 8 + (l >> 3);
    vcol[j] = ((l & 7) * 16) ^ ((vrow4[j] & 7) << 4);
  }
  int xr = (l16 & 7) << 4;

  #pragma unroll 1
  for (int pj = 0; pj < 2; ++pj) {
    int qt = pj ? 31 - pair : pair;
    int nst = qt + 1;
    int c0 = (nst + 1) >> 1;
    int t0 = half ? c0 : 0;
    int cnt = half ? nst - c0 : c0;
    int q0 = qt * 64 + w * 16;
    int qg = q0 + l16;

    bf16x8 qf[4];
    const unsigned short* Qrow = Qb + ((size_t)(bh * 2048 + qg)) * 128;
    #pragma unroll
    for (int kq = 0; kq < 4; ++kq)
      qf[kq] = *(const bf16x8*)&Qrow[kq * 32 + lh * 8];

    float m_l = -INFINITY, l_l = 0.f;
    f32x4 o_acc[8];
    #pragma unroll
    for (int c = 0; c < 8; ++c) o_acc[c] = (f32x4){0.f, 0.f, 0.f, 0.f};

    const float* simrow = sim + ((size_t)(b * 2048) + qg) * 2048;
    const float* mrow = npm + b * 2048;

    if (cnt > 0) {
      #pragma unroll
      for (int j = 0; j < 4; ++j) {
        int i = w * 4 + j;
        gload16(KbB + (size_t)(t0 * 64 + krow[j]) * 256 + kcol[j],
                &KsL[0][i * 1024]);
        gload16(VtB + (size_t)vrow4[j] * 4096 + (size_t)(t0 * 64) * 2 + vcol[j],
                &VtsL[0][i * 1024]);
      }
      asm volatile("s_waitcnt vmcnt(0)" ::: "memory");
      __syncthreads();

      #pragma unroll 1
      for (int ti = 0; ti < cnt; ++ti) {
        int cur = ti & 1;
        int kv0 = (t0 + ti) * 64;
        if (ti + 1 < cnt) {
          int kvn = kv0 + 64;
          #pragma unroll
          for (int j = 0; j < 4; ++j) {
            int i = w * 4 + j;
            gload16(KbB + (size_t)(kvn + krow[j]) * 256 + kcol[j],
                    &KsL[cur ^ 1][i * 1024]);
            gload16(VtB + (size_t)vrow4[j] * 4096 + (size_t)kvn * 2 + vcol[j],
                    &VtsL[cur ^ 1][i * 1024]);
          }
        }
        const char* Kbase = KsL[cur];
        f32x4 sc[4];
        #pragma unroll
        for (int tt = 0; tt < 4; ++tt) {
          sc[tt] = (f32x4){0.f, 0.f, 0.f, 0.f};
          const char* Krow = Kbase + (tt * 16 + l16) * 256;
          #pragma unroll
          for (int kq = 0; kq < 4; ++kq) {
            bf16x8 kf = *(const bf16x8*)(Krow + ((kq * 64 + lh * 16) ^ xr));
            sc[tt] = __builtin_amdgcn_mfma_f32_16x16x32_bf16(kf, qf[kq], sc[tt], 0, 0, 0);
          }
        }
        float4 sim4[4], mk4[4];
        #pragma unroll
        for (int tt = 0; tt < 4; ++tt) {
          sim4[tt] = *(const float4*)&simrow[kv0 + tt * 16 + lh * 4];
          mk4[tt] = *(const float4*)&mrow[kv0 + tt * 16 + lh * 4];
        }
        float sv[4][4];
        #pragma unroll
        for (int tt = 0; tt < 4; ++tt) {
          #pragma unroll
          for (int r = 0; r < 4; ++r) {
            int kvg = kv0 + tt * 16 + lh * 4 + r;
            float mkr = r == 0 ? mk4[tt].x : r == 1 ? mk4[tt].y
                      : r == 2 ? mk4[tt].z : mk4[tt].w;
            float smr = r == 0 ? sim4[tt].x : r == 1 ? sim4[tt].y
                      : r == 2 ? sim4[tt].z : sim4[tt].w;
            bool valid = (kvg <= qg) && (mkr != 0.f);
            sv[tt][r] = valid ? sc[tt][r] * 0.08838834764831845f + smr : -1e9f;
          }
        }
        float mx = sv[0][0];
        #pragma unroll
        for (int tt = 0; tt < 4; ++tt)
          #pragma unroll
          for (int r = 0; r < 4; ++r) mx = fmaxf(mx, sv[tt][r]);
        mx = fmaxf(mx, __shfl_xor(mx, 16));
        mx = fmaxf(mx, __shfl_xor(mx, 32));
        float mn = fmaxf(m_l, mx);
        float alpha = __expf(m_l - mn);
        m_l = mn;
        float ts = 0.f;
        #pragma unroll
        for (int tt = 0; tt < 4; ++tt)
          #pragma unroll
          for (int r = 0; r < 4; ++r) {
            float ppv = __expf(sv[tt][r] - mn);
            sv[tt][r] = ppv;
            ts += ppv;
          }
        ts += __shfl_xor(ts, 16);
        ts += __shfl_xor(ts, 32);
        l_l = l_l * alpha + ts;
        #pragma unroll
        for (int tt = 0; tt < 4; ++tt) {
          u16x4 pw;
          pw[0] = f2bf(sv[tt][0]); pw[1] = f2bf(sv[tt][1]);
          pw[2] = f2bf(sv[tt][2]); pw[3] = f2bf(sv[tt][3]);
          *(u16x4*)&Pl[w][l16][tt * 16 + lh * 4] = pw;
        }
        float al[4];
        #pragma unroll
        for (int r = 0; r < 4; ++r) al[r] = __shfl(alpha, lh * 4 + r);
        #pragma unroll
        for (int c = 0; c < 8; ++c)
          #pragma unroll
          for (int r = 0; r < 4; ++r) o_acc[c][r] *= al[r];
        const char* Vbase = VtsL[cur];
        #pragma unroll
        for (int kf2 = 0; kf2 < 2; ++kf2) {
          bf16x8 pa = *(bf16x8*)&Pl[w][l16][kf2 * 32 + lh * 8];
          #pragma unroll
          for (int c = 0; c < 8; ++c) {
            bf16x8 vf = *(const bf16x8*)(Vbase + (c * 16 + l16) * 128 +
                                         ((kf2 * 64 + lh * 16) ^ xr));
            o_acc[c] = __builtin_amdgcn_mfma_f32_16x16x32_bf16(pa, vf, o_acc[c], 0, 0, 0);
          }
        }
        asm volatile("s_waitcnt vmcnt(0)" ::: "memory");
        __syncthreads();
      }
    }
    #pragma unroll
    for (int r = 0; r < 4; ++r) {
      int qgr = q0 + lh * 4 + r;
      unsigned short* op = Op + ((size_t)(bh * 2048 + qgr)) * 128;
      #pragma unroll
      for (int c = 0; c < 8; ++c) op[c * 16 + l16] = f2bf(o_acc[c][r]);
    }
    if (lh == 0) {
      float2 v; v.x = m_l; v.y = l_l;
      ml[bh * 2048 + q0 + l16] = v;
    }
    __syncthreads();
  }
}

// ---------------- combine partials -> final attn output (token-major bf16) ------
__global__ __launch_bounds__(256) void attn_combine_kernel(
    const unsigned short* __restrict__ Op0, const unsigned short* __restrict__ Op1,
    const float2* __restrict__ ml0, const float2* __restrict__ ml1,
    unsigned short* __restrict__ Of) {
  int idx = blockIdx.x * 256 + threadIdx.x;
  int row = idx >> 4;
  int d0 = (idx & 15) * 8;
  float2 a = ml0[row], c2 = ml1[row];
  float m = fmaxf(a.x, c2.x);
  float e1 = __expf(a.x - m), e2 = __expf(c2.x - m);
  float inv = 1.f / (e1 * a.y + e2 * c2.y);
  u16x8 o1 = *(const u16x8*)&Op0[(size_t)row * 128 + d0];
  u16x8 o2 = *(const u16x8*)&Op1[(size_t)row * 128 + d0];
  int bh = row >> 11, q = row & 2047;
  int b = bh >> 2, h = bh & 3;
  unsigned short* dst = Of + ((size_t)(b * 2048 + q)) * 512 + h * 128 + d0;
  u16x8 o;
  #pragma unroll
  for (int j = 0; j < 8; ++j)
    o[j] = f2bf((bf2f(o1[j]) * e1 + bf2f(o2[j]) * e2) * inv);
  *(u16x8*)dst = o;
}

// ---------------- layernorm (+ optional bf16 copy) ----------------
__global__ __launch_bounds__(256) void ln_kernel(
    const float* __restrict__ x, const float* __restrict__ res,
    const float* __restrict__ g, const float* __restrict__ bta,
    const float* __restrict__ npm, float* __restrict__ out,
    unsigned short* __restrict__ out16) {
  __shared__ float ssum[4], ssq[4];
  int row = blockIdx.x;
  int tid = threadIdx.x;
  size_t base = (size_t)row * DM_;
  float v0 = x[base + tid] + res[base + tid];
  float v1 = x[base + tid + 256] + res[base + tid + 256];
  float sum = v0 + v1, sq = v0 * v0 + v1 * v1;
  #pragma unroll
  for (int off = 32; off >= 1; off >>= 1) {
    sum += __shfl_down(sum, off);
    sq += __shfl_down(sq, off);
  }
  int wid = tid >> 6, lane = tid & 63;
  if (lane == 0) { ssum[wid] = sum; ssq[wid] = sq; }
  __syncthreads();
  sum = ssum[0] + ssum[1] + ssum[2] + ssum[3];
  sq = ssq[0] + ssq[1] + ssq[2] + ssq[3];
  float mean = sum * (1.f / DM_);
  float var = sq * (1.f / DM_) - mean * mean;
  float rs = rsqrtf(var + 1e-5f);
  float mask = npm[row];
  float o0 = ((v0 - mean) * rs * g[tid] + bta[tid]) * mask;
  float o1 = ((v1 - mean) * rs * g[tid + 256] + bta[tid + 256]) * mask;
  out[base + tid] = o0;
  out[base + tid + 256] = o1;
  if (out16) {
    out16[base + tid] = f2bf(o0);
    out16[base + tid + 256] = f2bf(o1);
  }
}

extern "C" void kernel_launch(void* const* d_in, const int* in_sizes, int n_in,
                              void* d_out, int out_size, void* d_ws,
                              size_t ws_size, hipStream_t stream) {
  const int* et = (const int*)d_in[0];
  const int* vx = (const int*)d_in[1];
  const float* tmv = (const float*)d_in[2];
  const float* npm = (const float*)d_in[3];
  const float* Amat = (const float*)d_in[4];
  const float* Wmat = (const float*)d_in[5];
  const float* eemb = (const float*)d_in[6];
  const float* vemb = (const float*)d_in[7];
  const float* Wq = (const float*)d_in[8];
  const float* Wk = (const float*)d_in[9];
  const float* Wv = (const float*)d_in[10];
  const float* Wo = (const float*)d_in[11];
  const float* bo = (const float*)d_in[12];
  const float* ln1g = (const float*)d_in[13];
  const float* ln1b = (const float*)d_in[14];
  const float* w1 = (const float*)d_in[15];
  const float* b1 = (const float*)d_in[16];
  const float* w2 = (const float*)d_in[17];
  const float* b2 = (const float*)d_in[18];
  const float* ln2g = (const float*)d_in[19];
  const float* ln2b = (const float*)d_in[20];

  float* out = (float*)d_out;
  float* enc_out = out;
  float* sim_out = out + (size_t)B_ * S_ * DM_;

  const size_t MB = 1ull << 20;
  char* wsb = (char*)d_ws;
  float* enc0 = (float*)(wsb + 0);                             // 0-16: live to LN1
  unsigned short* enc0b = (unsigned short*)(wsb + 16 * MB);    // 16-24
  unsigned short* WqT = (unsigned short*)(wsb + 24 * MB);      // 24-28: weights
  unsigned short* WkT = WqT + 512 * 512;
  unsigned short* WvT = WkT + 512 * 512;
  unsigned short* WoT = WvT + 512 * 512;
  unsigned short* w1T = WoT + 512 * 512;
  unsigned short* w2T = w1T + 1024 * 512;
  unsigned short* Qb16 = (unsigned short*)(wsb + 28 * MB);     // 28-36
  unsigned short* Kb16 = (unsigned short*)(wsb + 36 * MB);     // 36-44
  unsigned short* Vt16 = (unsigned short*)(wsb + 44 * MB);     // 44-52
  unsigned short* Op0 = (unsigned short*)(wsb + 52 * MB);      // 52-60 partial half0
  unsigned short* Op1 = enc0b;                                 // 16-24 partial half1
  float2* ml0 = (float2*)(wsb + 60 * MB);                      // 60-60.25
  float2* ml1 = ml0 + 32768;                                   // 60.25-60.5
  unsigned short* Of16 = Qb16;           // 28-36 (Q dead after attn)
  float* OP = (float*)(wsb + 88 * MB);   // 88-104
  float* enc1 = OP;                      // LN1 in-place
  unsigned short* enc1b = enc0b;         // 16-24 (Op1 dead after combine)
  unsigned short* hid = Kb16;            // 36-52 (K,V dead after attn)
  float* fbuf = (float*)(wsb + 52 * MB); // 52-68 (Op0/ml dead after combine)
  unsigned short* AWb = (unsigned short*)(wsb + 104 * MB);     // 104-154: bf16 AW
  int useAW = (ws_size >= 104 * MB + (size_t)NV_ * NV_ * 2) ? 1 : 0;

  int M = B_ * S_;

  if (useAW)
    aw_kernel<<<dim3(1024), dim3(256), 0, stream>>>(Amat, Wmat, AWb);

  ew_kernel<<<dim3(10240), dim3(256), 0, stream>>>(
      et, vx, tmv, npm, eemb, vemb, Wq, Wk, Wv, Wo, w1, w2,
      enc0, enc0b, WqT, WkT, WvT, WoT, w1T, w2T);

  simqkv_kernel<<<dim3(9728), dim3(256), 0, stream>>>(
      vx, Amat, Wmat, AWb, sim_out, enc0b, WqT, Qb16, useAW);

  attn_mfma_kernel<<<dim3(512), dim3(256), 0, stream>>>(
      Qb16, Kb16, Vt16, sim_out, npm, Op0, Op1, ml0, ml1);
  attn_combine_kernel<<<dim3(2048), dim3(256), 0, stream>>>(
      Op0, Op1, ml0, ml1, Of16);

  gemm_bf16_kernel<0, false, 64><<<dim3(4, 128), dim3(256), 0, stream>>>(
      Of16, WoT, bo, OP, M, DM_, DM_);
  ln_kernel<<<dim3(M), dim3(256), 0, stream>>>(OP, enc0, ln1g, ln1b, npm, enc1,
                                               enc1b);

  gemm_bf16_kernel<1, true, 64><<<dim3(8, 128), dim3(256), 0, stream>>>(
      enc1b, w1T, b1, hid, M, DI_, DM_);
  gemm_bf16_kernel<0, false, 64><<<dim3(4, 128), dim3(256), 0, stream>>>(
      hid, w2T, b2, fbuf, M, DM_, DI_);
  ln_kernel<<<dim3(M), dim3(256), 0, stream>>>(fbuf, enc1, ln2g, ln2b, npm,
                                               enc_out, nullptr);
}

// Round 25
// 259.195 us; speedup vs baseline: 1.1006x; 1.0771x over previous
//
#include <hip/hip_runtime.h>
#include <hip/hip_bf16.h>

#define B_ 4
#define S_ 2048
#define DM_ 512
#define H_ 4
#define DK_ 128
#define DI_ 1024
#define NV_ 5000

typedef __attribute__((ext_vector_type(8))) short bf16x8;
typedef __attribute__((ext_vector_type(8))) unsigned short u16x8;
typedef __attribute__((ext_vector_type(4))) unsigned short u16x4;
typedef __attribute__((ext_vector_type(4))) float f32x4;

__device__ inline unsigned short f2bf(float x) {
  unsigned int u = __float_as_uint(x);
  unsigned int r = (u + 0x7fffu + ((u >> 16) & 1u)) >> 16;
  return (unsigned short)r;
}
__device__ inline float bf2f(unsigned short u) {
  return __uint_as_float(((unsigned int)u) << 16);
}
__device__ inline void gload16(const void* g, void* l) {
  __builtin_amdgcn_global_load_lds(
      (const __attribute__((address_space(1))) void*)g,
      (__attribute__((address_space(3))) void*)l, 16, 0, 0);
}

// ---------------- kernel A: embed (0-8191) | wt (8192-10239) ----------------
__global__ __launch_bounds__(256) void ew_kernel(
    const int* __restrict__ et, const int* __restrict__ vx,
    const float* __restrict__ tmv, const float* __restrict__ npm,
    const float* __restrict__ eemb, const float* __restrict__ vemb,
    const float* __restrict__ Wq, const float* __restrict__ Wk,
    const float* __restrict__ Wv, const float* __restrict__ Wo,
    const float* __restrict__ w1, const float* __restrict__ w2,
    float* __restrict__ enc0, unsigned short* __restrict__ enc0b,
    unsigned short* __restrict__ WqT, unsigned short* __restrict__ WkT,
    unsigned short* __restrict__ WvT, unsigned short* __restrict__ WoT,
    unsigned short* __restrict__ w1T, unsigned short* __restrict__ w2T) {
  __shared__ unsigned short T[32][40];
  int bid = blockIdx.x;
  int tid = threadIdx.x;
  if (bid < 8192) {
    int row = bid;
    int t = et[row], v = vx[row];
    float time = tmv[row], mask = npm[row];
    #pragma unroll
    for (int k = 0; k < 2; ++k) {
      int dd = tid + k * 256;
      float pvinv = __expf((float)(dd & ~1) * -0.017988946039015984f);
      float r = time * pvinv;
      float tem = (((dd & 1) == 0) ? sinf(r) : cosf(r)) * mask;
      float val = eemb[(size_t)t * DM_ + dd] + vemb[(size_t)v * DM_ + dd] + tem;
      enc0[(size_t)row * DM_ + dd] = val;
      enc0b[(size_t)row * DM_ + dd] = f2bf(val);
    }
  } else {
    int wb = bid - 8192;
    const float* src; unsigned short* dst; int K, N, lid;
    if (wb < 256)       { src = Wq; dst = WqT; K = 512;  N = 512;  lid = wb; }
    else if (wb < 512)  { src = Wk; dst = WkT; K = 512;  N = 512;  lid = wb - 256; }
    else if (wb < 768)  { src = Wv; dst = WvT; K = 512;  N = 512;  lid = wb - 512; }
    else if (wb < 1024) { src = Wo; dst = WoT; K = 512;  N = 512;  lid = wb - 768; }
    else if (wb < 1536) { src = w1; dst = w1T; K = 512;  N = 1024; lid = wb - 1024; }
    else                { src = w2; dst = w2T; K = 1024; N = 512;  lid = wb - 1536; }
    int nt = N / 32;
    int n0 = (lid % nt) * 32, k0 = (lid / nt) * 32;
    int r = tid >> 3, c0 = (tid & 7) * 4;
    float4 v = *(const float4*)&src[(size_t)(k0 + r) * N + n0 + c0];
    T[r][c0 + 0] = f2bf(v.x);
    T[r][c0 + 1] = f2bf(v.y);
    T[r][c0 + 2] = f2bf(v.z);
    T[r][c0 + 3] = f2bf(v.w);
    __syncthreads();
    u16x4 o;
    o[0] = T[c0 + 0][r]; o[1] = T[c0 + 1][r];
    o[2] = T[c0 + 2][r]; o[3] = T[c0 + 3][r];
    *(u16x4*)&dst[(size_t)(n0 + r) * K + k0 + c0] = o;
  }
}

// ---------------- kernel B: sim | fused QKV GEMM, INTERLEAVED block IDs ----------
// 9728 blocks = 512 groups x (16 sim + 3 qkv): QKV co-resident with sim throughout.
__global__ __launch_bounds__(256) void simqkv_kernel(
    const int* __restrict__ vx, const float* __restrict__ A,
    const float* __restrict__ W, float* __restrict__ sim,
    const unsigned short* __restrict__ enc0b, const unsigned short* __restrict__ BT,
    unsigned short* __restrict__ QKV) {
  __shared__ __attribute__((aligned(16))) char arena[40960];
  int bid = blockIdx.x;
  int tid = threadIdx.x;
  int g = bid / 19, rr = bid % 19;
  if (rr < 16) {
    // ---- sim job g*16+rr ----
    int job = g * 16 + rr;
    float* Ar = (float*)arena;             // 20 KB
    float* Wr = (float*)(arena + 20480);   // 20 KB
    int i = job & 2047;
    int b = job >> 11;
    int vi = vx[b * S_ + i];
    float* out = sim + ((size_t)(b * S_ + i)) * S_;
    if (vi == 0) {
      for (int j = tid * 4; j < S_; j += 1024)
        *(float4*)&out[j] = (float4){0.f, 0.f, 0.f, 0.f};
      return;
    }
    int w = tid >> 6, l = tid & 63;
    const char* Abase = (const char*)(A + (size_t)(vi - 1) * NV_);
    const char* Wbase = (const char*)(W + (size_t)(vi - 1) * NV_);
    #pragma unroll
    for (int it = 0; it < 5; ++it) {
      int seg = it * 4 + w;
      int chunk = seg * 64 + l;
      if (chunk < 1250) {
        gload16(Abase + (size_t)chunk * 16, (char*)Ar + seg * 1024);
        gload16(Wbase + (size_t)chunk * 16, (char*)Wr + seg * 1024);
      }
    }
    asm volatile("s_waitcnt vmcnt(0)" ::: "memory");
    __syncthreads();
    for (int j = tid * 4; j < S_; j += 1024) {
      int4 vj = *(const int4*)&vx[b * S_ + j];
      float4 o;
      o.x = vj.x ? Ar[vj.x - 1] * Wr[vj.x - 1] * 10.0f : 0.f;
      o.y = vj.y ? Ar[vj.y - 1] * Wr[vj.y - 1] * 10.0f : 0.f;
      o.z = vj.z ? Ar[vj.z - 1] * Wr[vj.z - 1] * 10.0f : 0.f;
      o.w = vj.w ? Ar[vj.w - 1] * Wr[vj.w - 1] * 10.0f : 0.f;
      *(float4*)&out[j] = o;
    }
  } else {
    // ---- QKV GEMM job g*3+(rr-16): M=8192, N=1536, K=512; MT=64 ----
    unsigned short* As = (unsigned short*)arena;            // [64][72]
    unsigned short* Bs = (unsigned short*)(arena + 9216);   // [128][72]
    int qb = g * 3 + (rr - 16);      // 0..1535
    int bx = qb % 12, by = qb / 12;
    int w = tid >> 6, l = tid & 63;
    int l16 = l & 15, lh = l >> 4;
    int row0 = by * 64, col0 = bx * 128;
    int ra = tid >> 1, ha = (tid & 1) * 32;
    int ra2 = tid >> 2, ha2 = (tid & 3) * 16;
    f32x4 acc[4][2];
    #pragma unroll
    for (int m = 0; m < 4; ++m)
      #pragma unroll
      for (int n = 0; n < 2; ++n) acc[m][n] = (f32x4){0.f, 0.f, 0.f, 0.f};

    for (int k0 = 0; k0 < 512; k0 += 64) {
      __syncthreads();
      {
        const unsigned short* sa = &enc0b[(size_t)(row0 + ra2) * 512 + k0 + ha2];
        uint4 a0 = *(const uint4*)(sa);
        uint4 a1 = *(const uint4*)(sa + 8);
        *(uint4*)&As[ra2 * 72 + ha2 + 0] = a0;
        *(uint4*)&As[ra2 * 72 + ha2 + 8] = a1;
        const unsigned short* sb = &BT[(size_t)(col0 + ra) * 512 + k0 + ha];
        uint4 b0 = *(const uint4*)(sb);
        uint4 b1 = *(const uint4*)(sb + 8);
        uint4 b2 = *(const uint4*)(sb + 16);
        uint4 b3 = *(const uint4*)(sb + 24);
        *(uint4*)&Bs[ra * 72 + ha + 0] = b0;
        *(uint4*)&Bs[ra * 72 + ha + 8] = b1;
        *(uint4*)&Bs[ra * 72 + ha + 16] = b2;
        *(uint4*)&Bs[ra * 72 + ha + 24] = b3;
      }
      __syncthreads();
      #pragma unroll
      for (int kc = 0; kc < 2; ++kc) {
        bf16x8 af[4], bfr[2];
        #pragma unroll
        for (int m = 0; m < 4; ++m)
          af[m] = *(bf16x8*)&As[(m * 16 + l16) * 72 + kc * 32 + lh * 8];
        #pragma unroll
        for (int n = 0; n < 2; ++n)
          bfr[n] = *(bf16x8*)&Bs[(w * 32 + n * 16 + l16) * 72 + kc * 32 + lh * 8];
        #pragma unroll
        for (int m = 0; m < 4; ++m)
          #pragma unroll
          for (int n = 0; n < 2; ++n)
            acc[m][n] = __builtin_amdgcn_mfma_f32_16x16x32_bf16(af[m], bfr[n], acc[m][n], 0, 0, 0);
      }
    }
    #pragma unroll
    for (int m = 0; m < 4; ++m) {
      #pragma unroll
      for (int r = 0; r < 4; ++r) {
        int row = row0 + m * 16 + lh * 4 + r;
        #pragma unroll
        for (int n = 0; n < 2; ++n) {
          int colg = col0 + w * 32 + n * 16 + l16;
          float v = acc[m][n][r];
          int which = colg >> 9;       // 0=Q 1=K 2=V
          int cl = colg & 511;
          int b = row >> 11, s = row & 2047;
          int h = cl >> 7, d = cl & 127;
          unsigned short* base = QKV + (size_t)which * 4194304;
          if (which < 2)
            base[((size_t)((b * 4 + h) * 2048 + s)) * 128 + d] = f2bf(v);
          else
            base[((size_t)((b * 4 + h) * 128 + d)) * 2048 + s] = f2bf(v);
        }
      }
    }
  }
}

// ---------------- bf16 MFMA GEMM: C = A[M,K] @ BT[N,K]^T (+bias)(+relu) ----------
// OMODE: 0 = f32 [M][N]; 1 = bf16 [M][N]
template <int OMODE, bool RELU, int MT = 128>
__global__ __launch_bounds__(256) void gemm_bf16_kernel(
    const unsigned short* __restrict__ A, const unsigned short* __restrict__ BT,
    const float* __restrict__ bias, void* __restrict__ C,
    int M, int N, int K) {
  __shared__ __attribute__((aligned(16))) unsigned short As[MT][72];
  __shared__ __attribute__((aligned(16))) unsigned short Bs[128][72];
  int tid = threadIdx.x;
  int w = tid >> 6, l = tid & 63;
  int l16 = l & 15, lh = l >> 4;
  const int NFR = (MT == 128) ? 4 : 2;
  int wr = (MT == 128) ? (w >> 1) : 0;
  int wc = (MT == 128) ? (w & 1) : w;
  int row0 = blockIdx.y * MT, col0 = blockIdx.x * 128;
  int ra = tid >> 1, ha = (tid & 1) * 32;
  f32x4 acc[4][4];
  #pragma unroll
  for (int m = 0; m < 4; ++m)
    #pragma unroll
    for (int n = 0; n < NFR; ++n) acc[m][n] = (f32x4){0.f, 0.f, 0.f, 0.f};

  for (int k0 = 0; k0 < K; k0 += 64) {
    __syncthreads();
    if (MT == 128) {
      const unsigned short* sa = &A[(size_t)(row0 + ra) * K + k0 + ha];
      uint4 a0 = *(const uint4*)(sa);
      uint4 a1 = *(const uint4*)(sa + 8);
      uint4 a2 = *(const uint4*)(sa + 16);
      uint4 a3 = *(const uint4*)(sa + 24);
      *(uint4*)&As[ra][ha + 0] = a0;
      *(uint4*)&As[ra][ha + 8] = a1;
      *(uint4*)&As[ra][ha + 16] = a2;
      *(uint4*)&As[ra][ha + 24] = a3;
    } else {
      int ra2 = tid >> 2, ha2 = (tid & 3) * 16;
      const unsigned short* sa = &A[(size_t)(row0 + ra2) * K + k0 + ha2];
      uint4 a0 = *(const uint4*)(sa);
      uint4 a1 = *(const uint4*)(sa + 8);
      *(uint4*)&As[ra2][ha2 + 0] = a0;
      *(uint4*)&As[ra2][ha2 + 8] = a1;
    }
    {
      const unsigned short* sb = &BT[(size_t)(col0 + ra) * K + k0 + ha];
      uint4 b0 = *(const uint4*)(sb);
      uint4 b1 = *(const uint4*)(sb + 8);
      uint4 b2 = *(const uint4*)(sb + 16);
      uint4 b3 = *(const uint4*)(sb + 24);
      *(uint4*)&Bs[ra][ha + 0] = b0;
      *(uint4*)&Bs[ra][ha + 8] = b1;
      *(uint4*)&Bs[ra][ha + 16] = b2;
      *(uint4*)&Bs[ra][ha + 24] = b3;
    }
    __syncthreads();
    #pragma unroll
    for (int kc = 0; kc < 2; ++kc) {
      bf16x8 af[4], bfr[4];
      #pragma unroll
      for (int m = 0; m < 4; ++m)
        af[m] = *(bf16x8*)&As[wr * 64 + m * 16 + l16][kc * 32 + lh * 8];
      #pragma unroll
      for (int n = 0; n < NFR; ++n)
        bfr[n] = *(bf16x8*)&Bs[wc * (16 * NFR) + n * 16 + l16][kc * 32 + lh * 8];
      #pragma unroll
      for (int m = 0; m < 4; ++m)
        #pragma unroll
        for (int n = 0; n < NFR; ++n)
          acc[m][n] = __builtin_amdgcn_mfma_f32_16x16x32_bf16(af[m], bfr[n], acc[m][n], 0, 0, 0);
    }
  }
  #pragma unroll
  for (int m = 0; m < 4; ++m) {
    #pragma unroll
    for (int r = 0; r < 4; ++r) {
      int row = row0 + wr * 64 + m * 16 + lh * 4 + r;
      #pragma unroll
      for (int n = 0; n < NFR; ++n) {
        int colg = col0 + wc * (16 * NFR) + n * 16 + l16;
        float v = acc[m][n][r];
        if (bias) v += bias[colg];
        if (RELU) v = fmaxf(v, 0.f);
        if (OMODE == 0) {
          ((float*)C)[(size_t)row * N + colg] = v;
        } else {
          ((unsigned short*)C)[(size_t)row * N + colg] = f2bf(v);
        }
      }
    }
  }
}

// ---------------- MFMA flash attention: async gload_lds staging, swizzled tiles ----
__global__ __launch_bounds__(256) void attn_mfma_kernel(
    const unsigned short* __restrict__ Qb, const unsigned short* __restrict__ Kb,
    const unsigned short* __restrict__ Vt, const float* __restrict__ sim,
    const float* __restrict__ npm, unsigned short* __restrict__ Op0,
    unsigned short* __restrict__ Op1, float2* __restrict__ ml0,
    float2* __restrict__ ml1) {
  __shared__ __attribute__((aligned(16))) char KsL[2][16384];   // [64][128] bf16
  __shared__ __attribute__((aligned(16))) char VtsL[2][16384];  // [128][64] bf16
  __shared__ __attribute__((aligned(16))) unsigned short Pl[4][16][72];
  int bid = blockIdx.x;          // 0..511
  int xcd = bid & 7;
  int j0 = bid >> 3;             // 0..63
  int bh = xcd * 2 + (j0 & 1);
  int jj = j0 >> 1;              // 0..31
  int pair = jj & 15;
  int half = jj >> 4;
  int b = bh >> 2;
  int tid = threadIdx.x;
  int w = tid >> 6, l = tid & 63;
  int l16 = l & 15, lh = l >> 4;
  unsigned short* Op = half ? Op1 : Op0;
  float2* ml = half ? ml1 : ml0;

  const char* KbB = (const char*)Kb + (size_t)bh * 2048 * 256;
  const char* VtB = (const char*)Vt + (size_t)bh * 128 * 4096;
  int krow[4], kcol[4], vrow4[4], vcol[4];
  #pragma unroll
  for (int j = 0; j < 4; ++j) {
    int i = w * 4 + j;
    krow[j] = i * 4 + (l >> 4);
    kcol[j] = ((l & 15) * 16) ^ ((krow[j] & 7) << 4);
    vrow4[j] = i * 8 + (l >> 3);
    vcol[j] = ((l & 7) * 16) ^ ((vrow4[j] & 7) << 4);
  }
  int xr = (l16 & 7) << 4;

  #pragma unroll 1
  for (int pj = 0; pj < 2; ++pj) {
    int qt = pj ? 31 - pair : pair;
    int nst = qt + 1;
    int c0 = (nst + 1) >> 1;
    int t0 = half ? c0 : 0;
    int cnt = half ? nst - c0 : c0;
    int q0 = qt * 64 + w * 16;
    int qg = q0 + l16;

    bf16x8 qf[4];
    const unsigned short* Qrow = Qb + ((size_t)(bh * 2048 + qg)) * 128;
    #pragma unroll
    for (int kq = 0; kq < 4; ++kq)
      qf[kq] = *(const bf16x8*)&Qrow[kq * 32 + lh * 8];

    float m_l = -INFINITY, l_l = 0.f;
    f32x4 o_acc[8];
    #pragma unroll
    for (int c = 0; c < 8; ++c) o_acc[c] = (f32x4){0.f, 0.f, 0.f, 0.f};

    const float* simrow = sim + ((size_t)(b * 2048) + qg) * 2048;
    const float* mrow = npm + b * 2048;

    if (cnt > 0) {
      #pragma unroll
      for (int j = 0; j < 4; ++j) {
        int i = w * 4 + j;
        gload16(KbB + (size_t)(t0 * 64 + krow[j]) * 256 + kcol[j],
                &KsL[0][i * 1024]);
        gload16(VtB + (size_t)vrow4[j] * 4096 + (size_t)(t0 * 64) * 2 + vcol[j],
                &VtsL[0][i * 1024]);
      }
      asm volatile("s_waitcnt vmcnt(0)" ::: "memory");
      __syncthreads();

      #pragma unroll 1
      for (int ti = 0; ti < cnt; ++ti) {
        int cur = ti & 1;
        int kv0 = (t0 + ti) * 64;
        if (ti + 1 < cnt) {
          int kvn = kv0 + 64;
          #pragma unroll
          for (int j = 0; j < 4; ++j) {
            int i = w * 4 + j;
            gload16(KbB + (size_t)(kvn + krow[j]) * 256 + kcol[j],
                    &KsL[cur ^ 1][i * 1024]);
            gload16(VtB + (size_t)vrow4[j] * 4096 + (size_t)kvn * 2 + vcol[j],
                    &VtsL[cur ^ 1][i * 1024]);
          }
        }
        const char* Kbase = KsL[cur];
        f32x4 sc[4];
        #pragma unroll
        for (int tt = 0; tt < 4; ++tt) {
          sc[tt] = (f32x4){0.f, 0.f, 0.f, 0.f};
          const char* Krow = Kbase + (tt * 16 + l16) * 256;
          #pragma unroll
          for (int kq = 0; kq < 4; ++kq) {
            bf16x8 kf = *(const bf16x8*)(Krow + ((kq * 64 + lh * 16) ^ xr));
            sc[tt] = __builtin_amdgcn_mfma_f32_16x16x32_bf16(kf, qf[kq], sc[tt], 0, 0, 0);
          }
        }
        float4 sim4[4], mk4[4];
        #pragma unroll
        for (int tt = 0; tt < 4; ++tt) {
          sim4[tt] = *(const float4*)&simrow[kv0 + tt * 16 + lh * 4];
          mk4[tt] = *(const float4*)&mrow[kv0 + tt * 16 + lh * 4];
        }
        float sv[4][4];
        #pragma unroll
        for (int tt = 0; tt < 4; ++tt) {
          #pragma unroll
          for (int r = 0; r < 4; ++r) {
            int kvg = kv0 + tt * 16 + lh * 4 + r;
            float mkr = r == 0 ? mk4[tt].x : r == 1 ? mk4[tt].y
                      : r == 2 ? mk4[tt].z : mk4[tt].w;
            float smr = r == 0 ? sim4[tt].x : r == 1 ? sim4[tt].y
                      : r == 2 ? sim4[tt].z : sim4[tt].w;
            bool valid = (kvg <= qg) && (mkr != 0.f);
            sv[tt][r] = valid ? sc[tt][r] * 0.08838834764831845f + smr : -1e9f;
          }
        }
        float mx = sv[0][0];
        #pragma unroll
        for (int tt = 0; tt < 4; ++tt)
          #pragma unroll
          for (int r = 0; r < 4; ++r) mx = fmaxf(mx, sv[tt][r]);
        mx = fmaxf(mx, __shfl_xor(mx, 16));
        mx = fmaxf(mx, __shfl_xor(mx, 32));
        float mn = fmaxf(m_l, mx);
        float alpha = __expf(m_l - mn);
        m_l = mn;
        float ts = 0.f;
        #pragma unroll
        for (int tt = 0; tt < 4; ++tt)
          #pragma unroll
          for (int r = 0; r < 4; ++r) {
            float ppv = __expf(sv[tt][r] - mn);
            sv[tt][r] = ppv;
            ts += ppv;
          }
        ts += __shfl_xor(ts, 16);
        ts += __shfl_xor(ts, 32);
        l_l = l_l * alpha + ts;
        #pragma unroll
        for (int tt = 0; tt < 4; ++tt) {
          u16x4 pw;
          pw[0] = f2bf(sv[tt][0]); pw[1] = f2bf(sv[tt][1]);
          pw[2] = f2bf(sv[tt][2]); pw[3] = f2bf(sv[tt][3]);
          *(u16x4*)&Pl[w][l16][tt * 16 + lh * 4] = pw;
        }
        float al[4];
        #pragma unroll
        for (int r = 0; r < 4; ++r) al[r] = __shfl(alpha, lh * 4 + r);
        #pragma unroll
        for (int c = 0; c < 8; ++c)
          #pragma unroll
          for (int r = 0; r < 4; ++r) o_acc[c][r] *= al[r];
        const char* Vbase = VtsL[cur];
        #pragma unroll
        for (int kf2 = 0; kf2 < 2; ++kf2) {
          bf16x8 pa = *(bf16x8*)&Pl[w][l16][kf2 * 32 + lh * 8];
          #pragma unroll
          for (int c = 0; c < 8; ++c) {
            bf16x8 vf = *(const bf16x8*)(Vbase + (c * 16 + l16) * 128 +
                                         ((kf2 * 64 + lh * 16) ^ xr));
            o_acc[c] = __builtin_amdgcn_mfma_f32_16x16x32_bf16(pa, vf, o_acc[c], 0, 0, 0);
          }
        }
        asm volatile("s_waitcnt vmcnt(0)" ::: "memory");
        __syncthreads();
      }
    }
    #pragma unroll
    for (int r = 0; r < 4; ++r) {
      int qgr = q0 + lh * 4 + r;
      unsigned short* op = Op + ((size_t)(bh * 2048 + qgr)) * 128;
      #pragma unroll
      for (int c = 0; c < 8; ++c) op[c * 16 + l16] = f2bf(o_acc[c][r]);
    }
    if (lh == 0) {
      float2 v; v.x = m_l; v.y = l_l;
      ml[bh * 2048 + q0 + l16] = v;
    }
    __syncthreads();
  }
}

// ---------------- combine partials -> final attn output (token-major bf16) ------
__global__ __launch_bounds__(256) void attn_combine_kernel(
    const unsigned short* __restrict__ Op0, const unsigned short* __restrict__ Op1,
    const float2* __restrict__ ml0, const float2* __restrict__ ml1,
    unsigned short* __restrict__ Of) {
  int idx = blockIdx.x * 256 + threadIdx.x;
  int row = idx >> 4;
  int d0 = (idx & 15) * 8;
  float2 a = ml0[row], c2 = ml1[row];
  float m = fmaxf(a.x, c2.x);
  float e1 = __expf(a.x - m), e2 = __expf(c2.x - m);
  float inv = 1.f / (e1 * a.y + e2 * c2.y);
  u16x8 o1 = *(const u16x8*)&Op0[(size_t)row * 128 + d0];
  u16x8 o2 = *(const u16x8*)&Op1[(size_t)row * 128 + d0];
  int bh = row >> 11, q = row & 2047;
  int b = bh >> 2, h = bh & 3;
  unsigned short* dst = Of + ((size_t)(b * 2048 + q)) * 512 + h * 128 + d0;
  u16x8 o;
  #pragma unroll
  for (int j = 0; j < 8; ++j)
    o[j] = f2bf((bf2f(o1[j]) * e1 + bf2f(o2[j]) * e2) * inv);
  *(u16x8*)dst = o;
}

// ---------------- layernorm (+ optional bf16 copy) ----------------
__global__ __launch_bounds__(256) void ln_kernel(
    const float* __restrict__ x, const float* __restrict__ res,
    const float* __restrict__ g, const float* __restrict__ bta,
    const float* __restrict__ npm, float* __restrict__ out,
    unsigned short* __restrict__ out16) {
  __shared__ float ssum[4], ssq[4];
  int row = blockIdx.x;
  int tid = threadIdx.x;
  size_t base = (size_t)row * DM_;
  float v0 = x[base + tid] + res[base + tid];
  float v1 = x[base + tid + 256] + res[base + tid + 256];
  float sum = v0 + v1, sq = v0 * v0 + v1 * v1;
  #pragma unroll
  for (int off = 32; off >= 1; off >>= 1) {
    sum += __shfl_down(sum, off);
    sq += __shfl_down(sq, off);
  }
  int wid = tid >> 6, lane = tid & 63;
  if (lane == 0) { ssum[wid] = sum; ssq[wid] = sq; }
  __syncthreads();
  sum = ssum[0] + ssum[1] + ssum[2] + ssum[3];
  sq = ssq[0] + ssq[1] + ssq[2] + ssq[3];
  float mean = sum * (1.f / DM_);
  float var = sq * (1.f / DM_) - mean * mean;
  float rs = rsqrtf(var + 1e-5f);
  float mask = npm[row];
  float o0 = ((v0 - mean) * rs * g[tid] + bta[tid]) * mask;
  float o1 = ((v1 - mean) * rs * g[tid + 256] + bta[tid + 256]) * mask;
  out[base + tid] = o0;
  out[base + tid + 256] = o1;
  if (out16) {
    out16[base + tid] = f2bf(o0);
    out16[base + tid + 256] = f2bf(o1);
  }
}

extern "C" void kernel_launch(void* const* d_in, const int* in_sizes, int n_in,
                              void* d_out, int out_size, void* d_ws,
                              size_t ws_size, hipStream_t stream) {
  const int* et = (const int*)d_in[0];
  const int* vx = (const int*)d_in[1];
  const float* tmv = (const float*)d_in[2];
  const float* npm = (const float*)d_in[3];
  const float* Amat = (const float*)d_in[4];
  const float* Wmat = (const float*)d_in[5];
  const float* eemb = (const float*)d_in[6];
  const float* vemb = (const float*)d_in[7];
  const float* Wq = (const float*)d_in[8];
  const float* Wk = (const float*)d_in[9];
  const float* Wv = (const float*)d_in[10];
  const float* Wo = (const float*)d_in[11];
  const float* bo = (const float*)d_in[12];
  const float* ln1g = (const float*)d_in[13];
  const float* ln1b = (const float*)d_in[14];
  const float* w1 = (const float*)d_in[15];
  const float* b1 = (const float*)d_in[16];
  const float* w2 = (const float*)d_in[17];
  const float* b2 = (const float*)d_in[18];
  const float* ln2g = (const float*)d_in[19];
  const float* ln2b = (const float*)d_in[20];

  float* out = (float*)d_out;
  float* enc_out = out;
  float* sim_out = out + (size_t)B_ * S_ * DM_;

  const size_t MB = 1ull << 20;
  char* wsb = (char*)d_ws;
  float* enc0 = (float*)(wsb + 0);                             // 0-16: live to LN1
  unsigned short* enc0b = (unsigned short*)(wsb + 16 * MB);    // 16-24
  unsigned short* WqT = (unsigned short*)(wsb + 24 * MB);      // 24-28: weights
  unsigned short* WkT = WqT + 512 * 512;
  unsigned short* WvT = WkT + 512 * 512;
  unsigned short* WoT = WvT + 512 * 512;
  unsigned short* w1T = WoT + 512 * 512;
  unsigned short* w2T = w1T + 1024 * 512;
  unsigned short* Qb16 = (unsigned short*)(wsb + 28 * MB);     // 28-36
  unsigned short* Kb16 = (unsigned short*)(wsb + 36 * MB);     // 36-44
  unsigned short* Vt16 = (unsigned short*)(wsb + 44 * MB);     // 44-52
  unsigned short* Op0 = (unsigned short*)(wsb + 52 * MB);      // 52-60 partial half0
  unsigned short* Op1 = enc0b;                                 // 16-24 partial half1
  float2* ml0 = (float2*)(wsb + 60 * MB);                      // 60-60.25
  float2* ml1 = ml0 + 32768;                                   // 60.25-60.5
  unsigned short* Of16 = Qb16;           // 28-36 (Q dead after attn)
  float* OP = (float*)(wsb + 88 * MB);   // 88-104
  float* enc1 = OP;                      // LN1 in-place
  unsigned short* enc1b = enc0b;         // 16-24 (Op1 dead after combine)
  unsigned short* hid = Kb16;            // 36-52 (K,V dead after attn)
  float* fbuf = (float*)(wsb + 52 * MB); // 52-68 (Op0/ml dead after combine)

  int M = B_ * S_;

  ew_kernel<<<dim3(10240), dim3(256), 0, stream>>>(
      et, vx, tmv, npm, eemb, vemb, Wq, Wk, Wv, Wo, w1, w2,
      enc0, enc0b, WqT, WkT, WvT, WoT, w1T, w2T);

  simqkv_kernel<<<dim3(9728), dim3(256), 0, stream>>>(
      vx, Amat, Wmat, sim_out, enc0b, WqT, Qb16);

  attn_mfma_kernel<<<dim3(512), dim3(256), 0, stream>>>(
      Qb16, Kb16, Vt16, sim_out, npm, Op0, Op1, ml0, ml1);
  attn_combine_kernel<<<dim3(2048), dim3(256), 0, stream>>>(
      Op0, Op1, ml0, ml1, Of16);

  gemm_bf16_kernel<0, false, 64><<<dim3(4, 128), dim3(256), 0, stream>>>(
      Of16, WoT, bo, OP, M, DM_, DM_);
  ln_kernel<<<dim3(M), dim3(256), 0, stream>>>(OP, enc0, ln1g, ln1b, npm, enc1,
                                               enc1b);

  gemm_bf16_kernel<1, true, 64><<<dim3(8, 128), dim3(256), 0, stream>>>(
      enc1b, w1T, b1, hid, M, DI_, DM_);
  gemm_bf16_kernel<0, false, 64><<<dim3(4, 128), dim3(256), 0, stream>>>(
      hid, w2T, b2, fbuf, M, DM_, DI_);
  ln_kernel<<<dim3(M), dim3(256), 0, stream>>>(fbuf, enc1, ln2g, ln2b, npm,
                                               enc_out, nullptr);
}

// Round 26
// 255.498 us; speedup vs baseline: 1.1165x; 1.0145x over previous
//
#include <hip/hip_runtime.h>
#include <hip/hip_bf16.h>

#define B_ 4
#define S_ 2048
#define DM_ 512
#define H_ 4
#define DK_ 128
#define DI_ 1024
#define NV_ 5000

typedef __attribute__((ext_vector_type(8))) short bf16x8;
typedef __attribute__((ext_vector_type(8))) unsigned short u16x8;
typedef __attribute__((ext_vector_type(4))) unsigned short u16x4;
typedef __attribute__((ext_vector_type(4))) float f32x4;

__device__ inline unsigned short f2bf(float x) {
  unsigned int u = __float_as_uint(x);
  unsigned int r = (u + 0x7fffu + ((u >> 16) & 1u)) >> 16;
  return (unsigned short)r;
}
__device__ inline float bf2f(unsigned short u) {
  return __uint_as_float(((unsigned int)u) << 16);
}
__device__ inline void gload16(const void* g, void* l) {
  __builtin_amdgcn_global_load_lds(
      (const __attribute__((address_space(1))) void*)g,
      (__attribute__((address_space(3))) void*)l, 16, 0, 0);
}

// ---------------- kernel A: embed (0-8191) | wt (8192-10239) ----------------
__global__ __launch_bounds__(256) void ew_kernel(
    const int* __restrict__ et, const int* __restrict__ vx,
    const float* __restrict__ tmv, const float* __restrict__ npm,
    const float* __restrict__ eemb, const float* __restrict__ vemb,
    const float* __restrict__ Wq, const float* __restrict__ Wk,
    const float* __restrict__ Wv, const float* __restrict__ Wo,
    const float* __restrict__ w1, const float* __restrict__ w2,
    float* __restrict__ enc0, unsigned short* __restrict__ enc0b,
    unsigned short* __restrict__ WqT, unsigned short* __restrict__ WkT,
    unsigned short* __restrict__ WvT, unsigned short* __restrict__ WoT,
    unsigned short* __restrict__ w1T, unsigned short* __restrict__ w2T) {
  __shared__ unsigned short T[32][40];
  int bid = blockIdx.x;
  int tid = threadIdx.x;
  if (bid < 8192) {
    int row = bid;
    int t = et[row], v = vx[row];
    float time = tmv[row], mask = npm[row];
    #pragma unroll
    for (int k = 0; k < 2; ++k) {
      int dd = tid + k * 256;
      float pvinv = __expf((float)(dd & ~1) * -0.017988946039015984f);
      float r = time * pvinv;
      float tem = (((dd & 1) == 0) ? sinf(r) : cosf(r)) * mask;
      float val = eemb[(size_t)t * DM_ + dd] + vemb[(size_t)v * DM_ + dd] + tem;
      enc0[(size_t)row * DM_ + dd] = val;
      enc0b[(size_t)row * DM_ + dd] = f2bf(val);
    }
  } else {
    int wb = bid - 8192;
    const float* src; unsigned short* dst; int K, N, lid;
    if (wb < 256)       { src = Wq; dst = WqT; K = 512;  N = 512;  lid = wb; }
    else if (wb < 512)  { src = Wk; dst = WkT; K = 512;  N = 512;  lid = wb - 256; }
    else if (wb < 768)  { src = Wv; dst = WvT; K = 512;  N = 512;  lid = wb - 512; }
    else if (wb < 1024) { src = Wo; dst = WoT; K = 512;  N = 512;  lid = wb - 768; }
    else if (wb < 1536) { src = w1; dst = w1T; K = 512;  N = 1024; lid = wb - 1024; }
    else                { src = w2; dst = w2T; K = 1024; N = 512;  lid = wb - 1536; }
    int nt = N / 32;
    int n0 = (lid % nt) * 32, k0 = (lid / nt) * 32;
    int r = tid >> 3, c0 = (tid & 7) * 4;
    float4 v = *(const float4*)&src[(size_t)(k0 + r) * N + n0 + c0];
    T[r][c0 + 0] = f2bf(v.x);
    T[r][c0 + 1] = f2bf(v.y);
    T[r][c0 + 2] = f2bf(v.z);
    T[r][c0 + 3] = f2bf(v.w);
    __syncthreads();
    u16x4 o;
    o[0] = T[c0 + 0][r]; o[1] = T[c0 + 1][r];
    o[2] = T[c0 + 2][r]; o[3] = T[c0 + 3][r];
    *(u16x4*)&dst[(size_t)(n0 + r) * K + k0 + c0] = o;
  }
}

// ---------------- kernel B: sim | fused QKV GEMM, INTERLEAVED block IDs ----------
// 9728 blocks = 512 groups x (16 sim + 3 qkv): QKV co-resident with sim throughout.
__global__ __launch_bounds__(256) void simqkv_kernel(
    const int* __restrict__ vx, const float* __restrict__ A,
    const float* __restrict__ W, float* __restrict__ sim,
    const unsigned short* __restrict__ enc0b, const unsigned short* __restrict__ BT,
    unsigned short* __restrict__ QKV) {
  __shared__ __attribute__((aligned(16))) char arena[40960];
  int bid = blockIdx.x;
  int tid = threadIdx.x;
  int g = bid / 19, rr = bid % 19;
  if (rr < 16) {
    // ---- sim job g*16+rr ----
    int job = g * 16 + rr;
    float* Ar = (float*)arena;             // 20 KB
    float* Wr = (float*)(arena + 20480);   // 20 KB
    int i = job & 2047;
    int b = job >> 11;
    int vi = vx[b * S_ + i];
    float* out = sim + ((size_t)(b * S_ + i)) * S_;
    if (vi == 0) {
      for (int j = tid * 4; j < S_; j += 1024)
        *(float4*)&out[j] = (float4){0.f, 0.f, 0.f, 0.f};
      return;
    }
    int w = tid >> 6, l = tid & 63;
    const char* Abase = (const char*)(A + (size_t)(vi - 1) * NV_);
    const char* Wbase = (const char*)(W + (size_t)(vi - 1) * NV_);
    #pragma unroll
    for (int it = 0; it < 5; ++it) {
      int seg = it * 4 + w;
      int chunk = seg * 64 + l;
      if (chunk < 1250) {
        gload16(Abase + (size_t)chunk * 16, (char*)Ar + seg * 1024);
        gload16(Wbase + (size_t)chunk * 16, (char*)Wr + seg * 1024);
      }
    }
    asm volatile("s_waitcnt vmcnt(0)" ::: "memory");
    __syncthreads();
    for (int j = tid * 4; j < S_; j += 1024) {
      int4 vj = *(const int4*)&vx[b * S_ + j];
      float4 o;
      o.x = vj.x ? Ar[vj.x - 1] * Wr[vj.x - 1] * 10.0f : 0.f;
      o.y = vj.y ? Ar[vj.y - 1] * Wr[vj.y - 1] * 10.0f : 0.f;
      o.z = vj.z ? Ar[vj.z - 1] * Wr[vj.z - 1] * 10.0f : 0.f;
      o.w = vj.w ? Ar[vj.w - 1] * Wr[vj.w - 1] * 10.0f : 0.f;
      *(float4*)&out[j] = o;
    }
  } else {
    // ---- QKV GEMM job g*3+(rr-16): M=8192, N=1536, K=512; MT=64 ----
    unsigned short* As = (unsigned short*)arena;            // [64][72]
    unsigned short* Bs = (unsigned short*)(arena + 9216);   // [128][72]
    int qb = g * 3 + (rr - 16);      // 0..1535
    int bx = qb % 12, by = qb / 12;
    int w = tid >> 6, l = tid & 63;
    int l16 = l & 15, lh = l >> 4;
    int row0 = by * 64, col0 = bx * 128;
    int ra = tid >> 1, ha = (tid & 1) * 32;
    int ra2 = tid >> 2, ha2 = (tid & 3) * 16;
    f32x4 acc[4][2];
    #pragma unroll
    for (int m = 0; m < 4; ++m)
      #pragma unroll
      for (int n = 0; n < 2; ++n) acc[m][n] = (f32x4){0.f, 0.f, 0.f, 0.f};

    for (int k0 = 0; k0 < 512; k0 += 64) {
      __syncthreads();
      {
        const unsigned short* sa = &enc0b[(size_t)(row0 + ra2) * 512 + k0 + ha2];
        uint4 a0 = *(const uint4*)(sa);
        uint4 a1 = *(const uint4*)(sa + 8);
        *(uint4*)&As[ra2 * 72 + ha2 + 0] = a0;
        *(uint4*)&As[ra2 * 72 + ha2 + 8] = a1;
        const unsigned short* sb = &BT[(size_t)(col0 + ra) * 512 + k0 + ha];
        uint4 b0 = *(const uint4*)(sb);
        uint4 b1 = *(const uint4*)(sb + 8);
        uint4 b2 = *(const uint4*)(sb + 16);
        uint4 b3 = *(const uint4*)(sb + 24);
        *(uint4*)&Bs[ra * 72 + ha + 0] = b0;
        *(uint4*)&Bs[ra * 72 + ha + 8] = b1;
        *(uint4*)&Bs[ra * 72 + ha + 16] = b2;
        *(uint4*)&Bs[ra * 72 + ha + 24] = b3;
      }
      __syncthreads();
      #pragma unroll
      for (int kc = 0; kc < 2; ++kc) {
        bf16x8 af[4], bfr[2];
        #pragma unroll
        for (int m = 0; m < 4; ++m)
          af[m] = *(bf16x8*)&As[(m * 16 + l16) * 72 + kc * 32 + lh * 8];
        #pragma unroll
        for (int n = 0; n < 2; ++n)
          bfr[n] = *(bf16x8*)&Bs[(w * 32 + n * 16 + l16) * 72 + kc * 32 + lh * 8];
        #pragma unroll
        for (int m = 0; m < 4; ++m)
          #pragma unroll
          for (int n = 0; n < 2; ++n)
            acc[m][n] = __builtin_amdgcn_mfma_f32_16x16x32_bf16(af[m], bfr[n], acc[m][n], 0, 0, 0);
      }
    }
    #pragma unroll
    for (int m = 0; m < 4; ++m) {
      #pragma unroll
      for (int r = 0; r < 4; ++r) {
        int row = row0 + m * 16 + lh * 4 + r;
        #pragma unroll
        for (int n = 0; n < 2; ++n) {
          int colg = col0 + w * 32 + n * 16 + l16;
          float v = acc[m][n][r];
          int which = colg >> 9;       // 0=Q 1=K 2=V
          int cl = colg & 511;
          int b = row >> 11, s = row & 2047;
          int h = cl >> 7, d = cl & 127;
          unsigned short* base = QKV + (size_t)which * 4194304;
          if (which < 2)
            base[((size_t)((b * 4 + h) * 2048 + s)) * 128 + d] = f2bf(v);
          else
            base[((size_t)((b * 4 + h) * 128 + d)) * 2048 + s] = f2bf(v);
        }
      }
    }
  }
}

// ---------------- bf16 MFMA GEMM: C = A[M,K] @ BT[N,K]^T (+bias)(+relu) ----------
// OMODE: 0 = f32 [M][N]; 1 = bf16 [M][N]
template <int OMODE, bool RELU, int MT = 128>
__global__ __launch_bounds__(256) void gemm_bf16_kernel(
    const unsigned short* __restrict__ A, const unsigned short* __restrict__ BT,
    const float* __restrict__ bias, void* __restrict__ C,
    int M, int N, int K) {
  __shared__ __attribute__((aligned(16))) unsigned short As[MT][72];
  __shared__ __attribute__((aligned(16))) unsigned short Bs[128][72];
  int tid = threadIdx.x;
  int w = tid >> 6, l = tid & 63;
  int l16 = l & 15, lh = l >> 4;
  const int NFR = (MT == 128) ? 4 : 2;
  int wr = (MT == 128) ? (w >> 1) : 0;
  int wc = (MT == 128) ? (w & 1) : w;
  int row0 = blockIdx.y * MT, col0 = blockIdx.x * 128;
  int ra = tid >> 1, ha = (tid & 1) * 32;
  f32x4 acc[4][4];
  #pragma unroll
  for (int m = 0; m < 4; ++m)
    #pragma unroll
    for (int n = 0; n < NFR; ++n) acc[m][n] = (f32x4){0.f, 0.f, 0.f, 0.f};

  for (int k0 = 0; k0 < K; k0 += 64) {
    __syncthreads();
    if (MT == 128) {
      const unsigned short* sa = &A[(size_t)(row0 + ra) * K + k0 + ha];
      uint4 a0 = *(const uint4*)(sa);
      uint4 a1 = *(const uint4*)(sa + 8);
      uint4 a2 = *(const uint4*)(sa + 16);
      uint4 a3 = *(const uint4*)(sa + 24);
      *(uint4*)&As[ra][ha + 0] = a0;
      *(uint4*)&As[ra][ha + 8] = a1;
      *(uint4*)&As[ra][ha + 16] = a2;
      *(uint4*)&As[ra][ha + 24] = a3;
    } else {
      int ra2 = tid >> 2, ha2 = (tid & 3) * 16;
      const unsigned short* sa = &A[(size_t)(row0 + ra2) * K + k0 + ha2];
      uint4 a0 = *(const uint4*)(sa);
      uint4 a1 = *(const uint4*)(sa + 8);
      *(uint4*)&As[ra2][ha2 + 0] = a0;
      *(uint4*)&As[ra2][ha2 + 8] = a1;
    }
    {
      const unsigned short* sb = &BT[(size_t)(col0 + ra) * K + k0 + ha];
      uint4 b0 = *(const uint4*)(sb);
      uint4 b1 = *(const uint4*)(sb + 8);
      uint4 b2 = *(const uint4*)(sb + 16);
      uint4 b3 = *(const uint4*)(sb + 24);
      *(uint4*)&Bs[ra][ha + 0] = b0;
      *(uint4*)&Bs[ra][ha + 8] = b1;
      *(uint4*)&Bs[ra][ha + 16] = b2;
      *(uint4*)&Bs[ra][ha + 24] = b3;
    }
    __syncthreads();
    #pragma unroll
    for (int kc = 0; kc < 2; ++kc) {
      bf16x8 af[4], bfr[4];
      #pragma unroll
      for (int m = 0; m < 4; ++m)
        af[m] = *(bf16x8*)&As[wr * 64 + m * 16 + l16][kc * 32 + lh * 8];
      #pragma unroll
      for (int n = 0; n < NFR; ++n)
        bfr[n] = *(bf16x8*)&Bs[wc * (16 * NFR) + n * 16 + l16][kc * 32 + lh * 8];
      #pragma unroll
      for (int m = 0; m < 4; ++m)
        #pragma unroll
        for (int n = 0; n < NFR; ++n)
          acc[m][n] = __builtin_amdgcn_mfma_f32_16x16x32_bf16(af[m], bfr[n], acc[m][n], 0, 0, 0);
    }
  }
  #pragma unroll
  for (int m = 0; m < 4; ++m) {
    #pragma unroll
    for (int r = 0; r < 4; ++r) {
      int row = row0 + wr * 64 + m * 16 + lh * 4 + r;
      #pragma unroll
      for (int n = 0; n < NFR; ++n) {
        int colg = col0 + wc * (16 * NFR) + n * 16 + l16;
        float v = acc[m][n][r];
        if (bias) v += bias[colg];
        if (RELU) v = fmaxf(v, 0.f);
        if (OMODE == 0) {
          ((float*)C)[(size_t)row * N + colg] = v;
        } else {
          ((unsigned short*)C)[(size_t)row * N + colg] = f2bf(v);
        }
      }
    }
  }
}

// ---------------- Wo GEMM with fused attention-combine on A-staging ----------
// A[row][col] = combine(Op0,Op1,ml0,ml1) at (bh=b*4+(col>>7), q=row&2047, d=col&127)
// M=8192, N=512, K=512, MT=64; epilogue f32 + bias.
__global__ __launch_bounds__(256) void gemm_wo_kernel(
    const unsigned short* __restrict__ Op0, const unsigned short* __restrict__ Op1,
    const float2* __restrict__ ml0, const float2* __restrict__ ml1,
    const unsigned short* __restrict__ BT, const float* __restrict__ bias,
    float* __restrict__ C) {
  __shared__ __attribute__((aligned(16))) unsigned short As[64][72];
  __shared__ __attribute__((aligned(16))) unsigned short Bs[128][72];
  int tid = threadIdx.x;
  int w = tid >> 6, l = tid & 63;
  int l16 = l & 15, lh = l >> 4;
  int row0 = blockIdx.y * 64, col0 = blockIdx.x * 128;
  int ra = tid >> 1, ha = (tid & 1) * 32;
  int ra2 = tid >> 2, ha2 = (tid & 3) * 16;
  int arow = row0 + ra2;               // token index
  int bq = arow & 2047, bb = arow >> 11;
  f32x4 acc[4][2];
  #pragma unroll
  for (int m = 0; m < 4; ++m)
    #pragma unroll
    for (int n = 0; n < 2; ++n) acc[m][n] = (f32x4){0.f, 0.f, 0.f, 0.f};

  for (int k0 = 0; k0 < 512; k0 += 64) {
    __syncthreads();
    {
      // fused combine for 16 columns c0..c0+15 (single head: 16 | 128)
      int c0 = k0 + ha2;
      int h = c0 >> 7, d0 = c0 & 127;
      int mlrow = (bb * 4 + h) * 2048 + bq;
      float2 a = ml0[mlrow], c2 = ml1[mlrow];
      float mm = fmaxf(a.x, c2.x);
      float e1 = __expf(a.x - mm), e2 = __expf(c2.x - mm);
      float inv = 1.f / (e1 * a.y + e2 * c2.y);
      size_t opo = ((size_t)mlrow) * 128 + d0;
      u16x8 x0 = *(const u16x8*)&Op0[opo];
      u16x8 x1 = *(const u16x8*)&Op0[opo + 8];
      u16x8 y0 = *(const u16x8*)&Op1[opo];
      u16x8 y1 = *(const u16x8*)&Op1[opo + 8];
      u16x8 o0, o1;
      #pragma unroll
      for (int j = 0; j < 8; ++j) {
        o0[j] = f2bf((bf2f(x0[j]) * e1 + bf2f(y0[j]) * e2) * inv);
        o1[j] = f2bf((bf2f(x1[j]) * e1 + bf2f(y1[j]) * e2) * inv);
      }
      *(u16x8*)&As[ra2][ha2 + 0] = o0;
      *(u16x8*)&As[ra2][ha2 + 8] = o1;
      const unsigned short* sb = &BT[(size_t)(col0 + ra) * 512 + k0 + ha];
      uint4 b0 = *(const uint4*)(sb);
      uint4 b1 = *(const uint4*)(sb + 8);
      uint4 b2 = *(const uint4*)(sb + 16);
      uint4 b3 = *(const uint4*)(sb + 24);
      *(uint4*)&Bs[ra][ha + 0] = b0;
      *(uint4*)&Bs[ra][ha + 8] = b1;
      *(uint4*)&Bs[ra][ha + 16] = b2;
      *(uint4*)&Bs[ra][ha + 24] = b3;
    }
    __syncthreads();
    #pragma unroll
    for (int kc = 0; kc < 2; ++kc) {
      bf16x8 af[4], bfr[2];
      #pragma unroll
      for (int m = 0; m < 4; ++m)
        af[m] = *(bf16x8*)&As[m * 16 + l16][kc * 32 + lh * 8];
      #pragma unroll
      for (int n = 0; n < 2; ++n)
        bfr[n] = *(bf16x8*)&Bs[w * 32 + n * 16 + l16][kc * 32 + lh * 8];
      #pragma unroll
      for (int m = 0; m < 4; ++m)
        #pragma unroll
        for (int n = 0; n < 2; ++n)
          acc[m][n] = __builtin_amdgcn_mfma_f32_16x16x32_bf16(af[m], bfr[n], acc[m][n], 0, 0, 0);
    }
  }
  #pragma unroll
  for (int m = 0; m < 4; ++m) {
    #pragma unroll
    for (int r = 0; r < 4; ++r) {
      int row = row0 + m * 16 + lh * 4 + r;
      #pragma unroll
      for (int n = 0; n < 2; ++n) {
        int colg = col0 + w * 32 + n * 16 + l16;
        C[(size_t)row * 512 + colg] = acc[m][n][r] + bias[colg];
      }
    }
  }
}

// ---------------- MFMA flash attention: async gload_lds staging, swizzled tiles ----
__global__ __launch_bounds__(256) void attn_mfma_kernel(
    const unsigned short* __restrict__ Qb, const unsigned short* __restrict__ Kb,
    const unsigned short* __restrict__ Vt, const float* __restrict__ sim,
    const float* __restrict__ npm, unsigned short* __restrict__ Op0,
    unsigned short* __restrict__ Op1, float2* __restrict__ ml0,
    float2* __restrict__ ml1) {
  __shared__ __attribute__((aligned(16))) char KsL[2][16384];   // [64][128] bf16
  __shared__ __attribute__((aligned(16))) char VtsL[2][16384];  // [128][64] bf16
  __shared__ __attribute__((aligned(16))) unsigned short Pl[4][16][72];
  int bid = blockIdx.x;          // 0..511
  int xcd = bid & 7;
  int j0 = bid >> 3;             // 0..63
  int bh = xcd * 2 + (j0 & 1);
  int jj = j0 >> 1;              // 0..31
  int pair = jj & 15;
  int half = jj >> 4;
  int b = bh >> 2;
  int tid = threadIdx.x;
  int w = tid >> 6, l = tid & 63;
  int l16 = l & 15, lh = l >> 4;
  unsigned short* Op = half ? Op1 : Op0;
  float2* ml = half ? ml1 : ml0;

  const char* KbB = (const char*)Kb + (size_t)bh * 2048 * 256;
  const char* VtB = (const char*)Vt + (size_t)bh * 128 * 4096;
  int krow[4], kcol[4], vrow4[4], vcol[4];
  #pragma unroll
  for (int j = 0; j < 4; ++j) {
    int i = w * 4 + j;
    krow[j] = i * 4 + (l >> 4);
    kcol[j] = ((l & 15) * 16) ^ ((krow[j] & 7) << 4);
    vrow4[j] = i * 8 + (l >> 3);
    vcol[j] = ((l & 7) * 16) ^ ((vrow4[j] & 7) << 4);
  }
  int xr = (l16 & 7) << 4;

  #pragma unroll 1
  for (int pj = 0; pj < 2; ++pj) {
    int qt = pj ? 31 - pair : pair;
    int nst = qt + 1;
    int c0 = (nst + 1) >> 1;
    int t0 = half ? c0 : 0;
    int cnt = half ? nst - c0 : c0;
    int q0 = qt * 64 + w * 16;
    int qg = q0 + l16;

    bf16x8 qf[4];
    const unsigned short* Qrow = Qb + ((size_t)(bh * 2048 + qg)) * 128;
    #pragma unroll
    for (int kq = 0; kq < 4; ++kq)
      qf[kq] = *(const bf16x8*)&Qrow[kq * 32 + lh * 8];

    float m_l = -INFINITY, l_l = 0.f;
    f32x4 o_acc[8];
    #pragma unroll
    for (int c = 0; c < 8; ++c) o_acc[c] = (f32x4){0.f, 0.f, 0.f, 0.f};

    const float* simrow = sim + ((size_t)(b * 2048) + qg) * 2048;
    const float* mrow = npm + b * 2048;

    if (cnt > 0) {
      #pragma unroll
      for (int j = 0; j < 4; ++j) {
        int i = w * 4 + j;
        gload16(KbB + (size_t)(t0 * 64 + krow[j]) * 256 + kcol[j],
                &KsL[0][i * 1024]);
        gload16(VtB + (size_t)vrow4[j] * 4096 + (size_t)(t0 * 64) * 2 + vcol[j],
                &VtsL[0][i * 1024]);
      }
      asm volatile("s_waitcnt vmcnt(0)" ::: "memory");
      __syncthreads();

      #pragma unroll 1
      for (int ti = 0; ti < cnt; ++ti) {
        int cur = ti & 1;
        int kv0 = (t0 + ti) * 64;
        if (ti + 1 < cnt) {
          int kvn = kv0 + 64;
          #pragma unroll
          for (int j = 0; j < 4; ++j) {
            int i = w * 4 + j;
            gload16(KbB + (size_t)(kvn + krow[j]) * 256 + kcol[j],
                    &KsL[cur ^ 1][i * 1024]);
            gload16(VtB + (size_t)vrow4[j] * 4096 + (size_t)kvn * 2 + vcol[j],
                    &VtsL[cur ^ 1][i * 1024]);
          }
        }
        const char* Kbase = KsL[cur];
        f32x4 sc[4];
        #pragma unroll
        for (int tt = 0; tt < 4; ++tt) {
          sc[tt] = (f32x4){0.f, 0.f, 0.f, 0.f};
          const char* Krow = Kbase + (tt * 16 + l16) * 256;
          #pragma unroll
          for (int kq = 0; kq < 4; ++kq) {
            bf16x8 kf = *(const bf16x8*)(Krow + ((kq * 64 + lh * 16) ^ xr));
            sc[tt] = __builtin_amdgcn_mfma_f32_16x16x32_bf16(kf, qf[kq], sc[tt], 0, 0, 0);
          }
        }
        float4 sim4[4], mk4[4];
        #pragma unroll
        for (int tt = 0; tt < 4; ++tt) {
          sim4[tt] = *(const float4*)&simrow[kv0 + tt * 16 + lh * 4];
          mk4[tt] = *(const float4*)&mrow[kv0 + tt * 16 + lh * 4];
        }
        float sv[4][4];
        #pragma unroll
        for (int tt = 0; tt < 4; ++tt) {
          #pragma unroll
          for (int r = 0; r < 4; ++r) {
            int kvg = kv0 + tt * 16 + lh * 4 + r;
            float mkr = r == 0 ? mk4[tt].x : r == 1 ? mk4[tt].y
                      : r == 2 ? mk4[tt].z : mk4[tt].w;
            float smr = r == 0 ? sim4[tt].x : r == 1 ? sim4[tt].y
                      : r == 2 ? sim4[tt].z : sim4[tt].w;
            bool valid = (kvg <= qg) && (mkr != 0.f);
            sv[tt][r] = valid ? sc[tt][r] * 0.08838834764831845f + smr : -1e9f;
          }
        }
        float mx = sv[0][0];
        #pragma unroll
        for (int tt = 0; tt < 4; ++tt)
          #pragma unroll
          for (int r = 0; r < 4; ++r) mx = fmaxf(mx, sv[tt][r]);
        mx = fmaxf(mx, __shfl_xor(mx, 16));
        mx = fmaxf(mx, __shfl_xor(mx, 32));
        float mn = fmaxf(m_l, mx);
        float alpha = __expf(m_l - mn);
        m_l = mn;
        float ts = 0.f;
        #pragma unroll
        for (int tt = 0; tt < 4; ++tt)
          #pragma unroll
          for (int r = 0; r < 4; ++r) {
            float ppv = __expf(sv[tt][r] - mn);
            sv[tt][r] = ppv;
            ts += ppv;
          }
        ts += __shfl_xor(ts, 16);
        ts += __shfl_xor(ts, 32);
        l_l = l_l * alpha + ts;
        #pragma unroll
        for (int tt = 0; tt < 4; ++tt) {
          u16x4 pw;
          pw[0] = f2bf(sv[tt][0]); pw[1] = f2bf(sv[tt][1]);
          pw[2] = f2bf(sv[tt][2]); pw[3] = f2bf(sv[tt][3]);
          *(u16x4*)&Pl[w][l16][tt * 16 + lh * 4] = pw;
        }
        float al[4];
        #pragma unroll
        for (int r = 0; r < 4; ++r) al[r] = __shfl(alpha, lh * 4 + r);
        #pragma unroll
        for (int c = 0; c < 8; ++c)
          #pragma unroll
          for (int r = 0; r < 4; ++r) o_acc[c][r] *= al[r];
        const char* Vbase = VtsL[cur];
        #pragma unroll
        for (int kf2 = 0; kf2 < 2; ++kf2) {
          bf16x8 pa = *(bf16x8*)&Pl[w][l16][kf2 * 32 + lh * 8];
          #pragma unroll
          for (int c = 0; c < 8; ++c) {
            bf16x8 vf = *(const bf16x8*)(Vbase + (c * 16 + l16) * 128 +
                                         ((kf2 * 64 + lh * 16) ^ xr));
            o_acc[c] = __builtin_amdgcn_mfma_f32_16x16x32_bf16(pa, vf, o_acc[c], 0, 0, 0);
          }
        }
        asm volatile("s_waitcnt vmcnt(0)" ::: "memory");
        __syncthreads();
      }
    }
    #pragma unroll
    for (int r = 0; r < 4; ++r) {
      int qgr = q0 + lh * 4 + r;
      unsigned short* op = Op + ((size_t)(bh * 2048 + qgr)) * 128;
      #pragma unroll
      for (int c = 0; c < 8; ++c) op[c * 16 + l16] = f2bf(o_acc[c][r]);
    }
    if (lh == 0) {
      float2 v; v.x = m_l; v.y = l_l;
      ml[bh * 2048 + q0 + l16] = v;
    }
    __syncthreads();
  }
}

// ---------------- layernorm (+ optional bf16 copy) ----------------
__global__ __launch_bounds__(256) void ln_kernel(
    const float* __restrict__ x, const float* __restrict__ res,
    const float* __restrict__ g, const float* __restrict__ bta,
    const float* __restrict__ npm, float* __restrict__ out,
    unsigned short* __restrict__ out16) {
  __shared__ float ssum[4], ssq[4];
  int row = blockIdx.x;
  int tid = threadIdx.x;
  size_t base = (size_t)row * DM_;
  float v0 = x[base + tid] + res[base + tid];
  float v1 = x[base + tid + 256] + res[base + tid + 256];
  float sum = v0 + v1, sq = v0 * v0 + v1 * v1;
  #pragma unroll
  for (int off = 32; off >= 1; off >>= 1) {
    sum += __shfl_down(sum, off);
    sq += __shfl_down(sq, off);
  }
  int wid = tid >> 6, lane = tid & 63;
  if (lane == 0) { ssum[wid] = sum; ssq[wid] = sq; }
  __syncthreads();
  sum = ssum[0] + ssum[1] + ssum[2] + ssum[3];
  sq = ssq[0] + ssq[1] + ssq[2] + ssq[3];
  float mean = sum * (1.f / DM_);
  float var = sq * (1.f / DM_) - mean * mean;
  float rs = rsqrtf(var + 1e-5f);
  float mask = npm[row];
  float o0 = ((v0 - mean) * rs * g[tid] + bta[tid]) * mask;
  float o1 = ((v1 - mean) * rs * g[tid + 256] + bta[tid + 256]) * mask;
  out[base + tid] = o0;
  out[base + tid + 256] = o1;
  if (out16) {
    out16[base + tid] = f2bf(o0);
    out16[base + tid + 256] = f2bf(o1);
  }
}

extern "C" void kernel_launch(void* const* d_in, const int* in_sizes, int n_in,
                              void* d_out, int out_size, void* d_ws,
                              size_t ws_size, hipStream_t stream) {
  const int* et = (const int*)d_in[0];
  const int* vx = (const int*)d_in[1];
  const float* tmv = (const float*)d_in[2];
  const float* npm = (const float*)d_in[3];
  const float* Amat = (const float*)d_in[4];
  const float* Wmat = (const float*)d_in[5];
  const float* eemb = (const float*)d_in[6];
  const float* vemb = (const float*)d_in[7];
  const float* Wq = (const float*)d_in[8];
  const float* Wk = (const float*)d_in[9];
  const float* Wv = (const float*)d_in[10];
  const float* Wo = (const float*)d_in[11];
  const float* bo = (const float*)d_in[12];
  const float* ln1g = (const float*)d_in[13];
  const float* ln1b = (const float*)d_in[14];
  const float* w1 = (const float*)d_in[15];
  const float* b1 = (const float*)d_in[16];
  const float* w2 = (const float*)d_in[17];
  const float* b2 = (const float*)d_in[18];
  const float* ln2g = (const float*)d_in[19];
  const float* ln2b = (const float*)d_in[20];

  float* out = (float*)d_out;
  float* enc_out = out;
  float* sim_out = out + (size_t)B_ * S_ * DM_;

  const size_t MB = 1ull << 20;
  char* wsb = (char*)d_ws;
  float* enc0 = (float*)(wsb + 0);                             // 0-16: live to LN1
  unsigned short* enc0b = (unsigned short*)(wsb + 16 * MB);    // 16-24
  unsigned short* WqT = (unsigned short*)(wsb + 24 * MB);      // 24-28: weights
  unsigned short* WkT = WqT + 512 * 512;
  unsigned short* WvT = WkT + 512 * 512;
  unsigned short* WoT = WvT + 512 * 512;
  unsigned short* w1T = WoT + 512 * 512;
  unsigned short* w2T = w1T + 1024 * 512;
  unsigned short* Qb16 = (unsigned short*)(wsb + 28 * MB);     // 28-36
  unsigned short* Kb16 = (unsigned short*)(wsb + 36 * MB);     // 36-44
  unsigned short* Vt16 = (unsigned short*)(wsb + 44 * MB);     // 44-52
  unsigned short* Op0 = (unsigned short*)(wsb + 52 * MB);      // 52-60 partial half0
  unsigned short* Op1 = enc0b;                                 // 16-24 partial half1
  float2* ml0 = (float2*)(wsb + 60 * MB);                      // 60-60.25
  float2* ml1 = ml0 + 32768;                                   // 60.25-60.5
  float* OP = (float*)(wsb + 88 * MB);   // 88-104
  float* enc1 = OP;                      // LN1 in-place
  unsigned short* enc1b = (unsigned short*)(wsb + 62 * MB);    // 62-70 (free region)
  unsigned short* hid = Kb16;            // 36-52 (K,V dead after attn)
  float* fbuf = (float*)(wsb + 70 * MB); // 70-86 (free region)

  int M = B_ * S_;

  ew_kernel<<<dim3(10240), dim3(256), 0, stream>>>(
      et, vx, tmv, npm, eemb, vemb, Wq, Wk, Wv, Wo, w1, w2,
      enc0, enc0b, WqT, WkT, WvT, WoT, w1T, w2T);

  simqkv_kernel<<<dim3(9728), dim3(256), 0, stream>>>(
      vx, Amat, Wmat, sim_out, enc0b, WqT, Qb16);

  attn_mfma_kernel<<<dim3(512), dim3(256), 0, stream>>>(
      Qb16, Kb16, Vt16, sim_out, npm, Op0, Op1, ml0, ml1);

  // Wo GEMM with fused combine (reads Op0/Op1/ml directly; no Of16)
  gemm_wo_kernel<<<dim3(4, 128), dim3(256), 0, stream>>>(
      Op0, Op1, ml0, ml1, WoT, bo, OP);
  ln_kernel<<<dim3(M), dim3(256), 0, stream>>>(OP, enc0, ln1g, ln1b, npm, enc1,
                                               enc1b);

  gemm_bf16_kernel<1, true, 64><<<dim3(8, 128), dim3(256), 0, stream>>>(
      enc1b, w1T, b1, hid, M, DI_, DM_);
  gemm_bf16_kernel<0, false, 64><<<dim3(4, 128), dim3(256), 0, stream>>>(
      hid, w2T, b2, fbuf, M, DM_, DI_);
  ln_kernel<<<dim3(M), dim3(256), 0, stream>>>(fbuf, enc1, ln2g, ln2b, npm,
                                               enc_out, nullptr);
}